// Round 1
// baseline (5401.675 us; speedup 1.0000x reference)
//
#include <hip/hip_runtime.h>
#include <math.h>

#define DEV __device__ __forceinline__

// B=4, S=1024, F=20, D=512, H=8, L=4, FF=2048, M=32, NH=3, D2=256, O=1, HD=64
constexpr int BSD = 4 * 1024 * 512; // B*S*D floats

DEV float wave_sum(float v) {
#pragma unroll
  for (int m = 32; m >= 1; m >>= 1) v += __shfl_xor(v, m, 64);
  return v;
}
DEV float wave_max(float v) {
#pragma unroll
  for (int m = 32; m >= 1; m >>= 1) v = fmaxf(v, __shfl_xor(v, m, 64));
  return v;
}
DEV float block_sum(float v, float* sm) {
  v = wave_sum(v);
  __syncthreads();
  if ((threadIdx.x & 63) == 0) sm[threadIdx.x >> 6] = v;
  __syncthreads();
  return sm[0] + sm[1] + sm[2] + sm[3];
}
DEV float block_max(float v, float* sm) {
  v = wave_max(v);
  __syncthreads();
  if ((threadIdx.x & 63) == 0) sm[threadIdx.x >> 6] = v;
  __syncthreads();
  return fmaxf(fmaxf(sm[0], sm[1]), fmaxf(sm[2], sm[3]));
}

// ---------------------------------------------------------------------------
// Input projection: h[r,:] = LN(x[r,:] @ in_W + in_b) * g + b  + posenc(s,:)
// one block per row (B*S rows), 256 threads, 2 cols/thread
// ---------------------------------------------------------------------------
__global__ __launch_bounds__(256) void k_inproj(
    const float* __restrict__ x, const float* __restrict__ W,
    const float* __restrict__ bias, const float* __restrict__ g,
    const float* __restrict__ bt, float* __restrict__ h) {
  int r = blockIdx.x;      // b*1024 + s
  int s = r & 1023;
  int t = threadIdx.x;
  __shared__ float xr[20];
  __shared__ float red[4];
  if (t < 20) xr[t] = x[r * 20 + t];
  __syncthreads();
  float o0 = bias[t], o1 = bias[t + 256];
#pragma unroll
  for (int f = 0; f < 20; f++) {
    float xv = xr[f];
    o0 += xv * W[f * 512 + t];
    o1 += xv * W[f * 512 + t + 256];
  }
  float mean = block_sum(o0 + o1, red) * (1.f / 512.f);
  float d0 = o0 - mean, d1 = o1 - mean;
  float var = block_sum(d0 * d0 + d1 * d1, red) * (1.f / 512.f);
  float rs = rsqrtf(var + 1e-5f);
  float n0 = d0 * rs * g[t] + bt[t];
  float n1 = d1 * rs * g[t + 256] + bt[t + 256];
  const float c1 = -9.210340371976184f / 512.f;  // -ln(10000)/D
  {
    int c = t;
    float div = expf((float)(c & ~1) * c1);
    float arg = (float)s * div;
    n0 += (c & 1) ? cosf(arg) : sinf(arg);
  }
  {
    int c = t + 256;
    float div = expf((float)(c & ~1) * c1);
    float arg = (float)s * div;
    n1 += (c & 1) ? cosf(arg) : sinf(arg);
  }
  float* hr = h + (size_t)r * 512;
  hr[t] = n0;
  hr[t + 256] = n1;
}

// ---------------------------------------------------------------------------
// Row LayerNorm over D=512. One block per row.
// ---------------------------------------------------------------------------
__global__ __launch_bounds__(256) void k_ln(
    const float* __restrict__ x, const float* __restrict__ g,
    const float* __restrict__ bt, float* __restrict__ y) {
  __shared__ float red[4];
  int r = blockIdx.x;
  int t = threadIdx.x;
  const float* xr = x + (size_t)r * 512;
  float v0 = xr[t], v1 = xr[t + 256];
  float mean = block_sum(v0 + v1, red) * (1.f / 512.f);
  float d0 = v0 - mean, d1 = v1 - mean;
  float var = block_sum(d0 * d0 + d1 * d1, red) * (1.f / 512.f);
  float rs = rsqrtf(var + 1e-5f);
  float* yr = y + (size_t)r * 512;
  yr[t] = d0 * rs * g[t] + bt[t];
  yr[t + 256] = d1 * rs * g[t + 256] + bt[t + 256];
}

// ---------------------------------------------------------------------------
// Tiled fp32 GEMM: C(M x N) = A(M x K) @ B(K x N) + bias, M fixed 4096 via grid
// BM=128 BN=64 BK=16, 256 threads, each thread 8x4 outputs (two row quads).
// MODE 0: bias; MODE 1: bias + residual in-place on C; MODE 2: bias + exact gelu
// ---------------------------------------------------------------------------
template <int MODE>
__global__ __launch_bounds__(256) void k_gemm(
    const float* __restrict__ A, const float* __restrict__ Bm,
    const float* __restrict__ bias, float* __restrict__ C, int N, int K) {
  __shared__ float As[16][132];  // stride-132 pad: A-writes 2-way, reads clean
  __shared__ float Bs[16][68];
  int t = threadIdx.x;
  int row0 = blockIdx.y * 128;
  int col0 = blockIdx.x * 64;
  float acc[2][4][4];
#pragma unroll
  for (int a = 0; a < 2; a++)
#pragma unroll
    for (int i = 0; i < 4; i++)
#pragma unroll
      for (int j = 0; j < 4; j++) acc[a][i][j] = 0.f;
  int tr = (t >> 4) << 2;   // 0..60
  int tc = (t & 15) << 2;   // 0..60
  for (int kb = 0; kb < K; kb += 16) {
#pragma unroll
    for (int i = 0; i < 2; i++) {
      int idx = t + (i << 8);
      int r = idx >> 2, k4 = (idx & 3) << 2;
      float4 av = *(const float4*)(A + (size_t)(row0 + r) * K + kb + k4);
      As[k4 + 0][r] = av.x;
      As[k4 + 1][r] = av.y;
      As[k4 + 2][r] = av.z;
      As[k4 + 3][r] = av.w;
    }
    {
      int rb = t >> 4, c4 = (t & 15) << 2;
      *(float4*)&Bs[rb][c4] = *(const float4*)(Bm + (size_t)(kb + rb) * N + col0 + c4);
    }
    __syncthreads();
#pragma unroll
    for (int kk = 0; kk < 16; kk++) {
      float4 a0 = *(const float4*)&As[kk][tr];
      float4 a1 = *(const float4*)&As[kk][tr + 64];
      float4 b0 = *(const float4*)&Bs[kk][tc];
      float ar0[4] = {a0.x, a0.y, a0.z, a0.w};
      float ar1[4] = {a1.x, a1.y, a1.z, a1.w};
      float br[4] = {b0.x, b0.y, b0.z, b0.w};
#pragma unroll
      for (int i = 0; i < 4; i++)
#pragma unroll
        for (int j = 0; j < 4; j++) {
          acc[0][i][j] += ar0[i] * br[j];
          acc[1][i][j] += ar1[i] * br[j];
        }
    }
    __syncthreads();
  }
#pragma unroll
  for (int a = 0; a < 2; a++)
#pragma unroll
    for (int i = 0; i < 4; i++) {
      int row = row0 + tr + a * 64 + i;
      float* Cr = C + (size_t)row * N + col0 + tc;
#pragma unroll
      for (int j = 0; j < 4; j++) {
        float vv = acc[a][i][j] + bias[col0 + tc + j];
        if (MODE == 1) vv += Cr[j];
        if (MODE == 2) vv = 0.5f * vv * (1.f + erff(vv * 0.70710678118654752f));
        Cr[j] = vv;
      }
    }
}

// ---------------------------------------------------------------------------
// Relative-position flash attention, fp32.
// grid (S/16, H, B); 256 threads = 4 waves; wave w owns query rows w*4..w*4+3.
// Online softmax; lane d accumulates o[row][d]. K/V tiles of 64 staged in LDS
// (stride 65 -> 2-way conflicts = free). rel factored via qrel[row][65].
// ---------------------------------------------------------------------------
__global__ __launch_bounds__(256) void k_attn(
    const float* __restrict__ q, const float* __restrict__ k,
    const float* __restrict__ v, const float* __restrict__ rel,
    float* __restrict__ out) {
  __shared__ float Ks[64][65];
  __shared__ float Vs[64][65];
  __shared__ float Qs[16][64];
  __shared__ float rels[65][65];
  __shared__ float qrl[16][66];
  int t = threadIdx.x;
  int lane = t & 63, w = t >> 6;
  int h = blockIdx.y, b = blockIdx.z;
  int qrow0 = blockIdx.x * 16;
  // stage Q (16 rows x 64)
  {
    int rr = t >> 4, f4 = (t & 15) << 2;
    *(float4*)&Qs[rr][f4] =
        *(const float4*)(q + (size_t)(b * 1024 + qrow0 + rr) * 512 + h * 64 + f4);
  }
  // stage rel (65 x 64) into padded LDS
#pragma unroll
  for (int i = 0; i < 5; i++) {
    int idx = t + (i << 8);
    if (idx < 1040) {
      int rr = idx >> 4, f4 = (idx & 15) << 2;
      float4 rv = *(const float4*)(rel + rr * 64 + f4);
      rels[rr][f4] = rv.x;
      rels[rr][f4 + 1] = rv.y;
      rels[rr][f4 + 2] = rv.z;
      rels[rr][f4 + 3] = rv.w;
    }
  }
  __syncthreads();
  // qrel[row][r] = q_row . rel[r]   (wave-private rows, no extra sync needed)
#pragma unroll
  for (int rr = 0; rr < 4; rr++) {
    int lrow = (w << 2) | rr;
#pragma unroll
    for (int rbase = 0; rbase <= 64; rbase += 64) {
      int r = rbase + lane;
      if (r < 65) {
        float s = 0.f;
#pragma unroll
        for (int d = 0; d < 64; d++) s += Qs[lrow][d] * rels[r][d];
        qrl[lrow][r] = s;
      }
    }
  }
  float m[4], l[4], o[4];
#pragma unroll
  for (int rr = 0; rr < 4; rr++) {
    m[rr] = -1e30f;
    l[rr] = 0.f;
    o[rr] = 0.f;
  }
  for (int kb = 0; kb < 1024; kb += 64) {
    __syncthreads();
#pragma unroll
    for (int i = 0; i < 4; i++) {
      int idx = t + (i << 8);
      int rr = idx >> 4, f4 = (idx & 15) << 2;
      float4 k4 = *(const float4*)(k + (size_t)(b * 1024 + kb + rr) * 512 + h * 64 + f4);
      Ks[rr][f4] = k4.x;
      Ks[rr][f4 + 1] = k4.y;
      Ks[rr][f4 + 2] = k4.z;
      Ks[rr][f4 + 3] = k4.w;
      float4 v4 = *(const float4*)(v + (size_t)(b * 1024 + kb + rr) * 512 + h * 64 + f4);
      Vs[rr][f4] = v4.x;
      Vs[rr][f4 + 1] = v4.y;
      Vs[rr][f4 + 2] = v4.z;
      Vs[rr][f4 + 3] = v4.w;
    }
    __syncthreads();
#pragma unroll
    for (int rr = 0; rr < 4; rr++) {
      int lrow = (w << 2) | rr;
      int ig = qrow0 + lrow;
      float s = 0.f;
#pragma unroll
      for (int d = 0; d < 64; d++) s += Qs[lrow][d] * Ks[lane][d];
      s *= 0.125f;  // 1/sqrt(64)
      int delta = kb + lane - ig;
      delta = delta < -32 ? -32 : (delta > 32 ? 32 : delta);
      s += qrl[lrow][delta + 32];
      float mt = wave_max(s);
      float mn = fmaxf(m[rr], mt);
      float sc = __expf(m[rr] - mn);
      float p = __expf(s - mn);
      float lt = wave_sum(p);
      l[rr] = l[rr] * sc + lt;
      o[rr] *= sc;
#pragma unroll
      for (int j = 0; j < 64; j++) {
        float pj = __shfl(p, j, 64);
        o[rr] += pj * Vs[j][lane];
      }
      m[rr] = mn;
    }
  }
#pragma unroll
  for (int rr = 0; rr < 4; rr++) {
    int lrow = (w << 2) | rr;
    out[(size_t)(b * 1024 + qrow0 + lrow) * 512 + h * 64 + lane] = o[rr] / l[rr];
  }
}

// ---------------------------------------------------------------------------
// Final global attention, last query row only. grid 32 = (b*8 + h).
// ---------------------------------------------------------------------------
__global__ __launch_bounds__(256) void k_gattn(
    const float* __restrict__ q, const float* __restrict__ k,
    const float* __restrict__ v, float* __restrict__ ctxa) {
  int t = threadIdx.x;
  int h = blockIdx.x & 7, b = blockIdx.x >> 3;
  __shared__ float Qs[64];
  __shared__ float sc[1024];
  __shared__ float red[4];
  __shared__ float op[4][64];
  if (t < 64) Qs[t] = q[(size_t)(b * 1024 + 1023) * 512 + h * 64 + t];
  __syncthreads();
  float lm = -1e30f;
  float sv[4];
#pragma unroll
  for (int jj = 0; jj < 4; jj++) {
    int j = t + (jj << 8);
    float s = 0.f;
#pragma unroll
    for (int d = 0; d < 64; d++) s += Qs[d] * k[(size_t)(b * 1024 + j) * 512 + h * 64 + d];
    s *= 0.125f;
    sv[jj] = s;
    lm = fmaxf(lm, s);
  }
  float bm = block_max(lm, red);
  float ls = 0.f;
#pragma unroll
  for (int jj = 0; jj < 4; jj++) {
    float e = __expf(sv[jj] - bm);
    sc[t + (jj << 8)] = e;
    ls += e;
  }
  float bs = block_sum(ls, red);  // syncs inside -> sc fully visible after
  int d = t & 63, qd = t >> 6;
  float acc = 0.f;
  for (int j = qd << 8; j < (qd << 8) + 256; j++)
    acc += sc[j] * v[(size_t)(b * 1024 + j) * 512 + h * 64 + d];
  op[qd][d] = acc;
  __syncthreads();
  if (t < 64) {
    float r = (op[0][t] + op[1][t] + op[2][t] + op[3][t]) / bs;
    ctxa[b * 512 + h * 64 + t] = r;
  }
}

// ---------------------------------------------------------------------------
// 4-row GEMM (ctx = attnlast @ gWo + gbo). grid 4 blocks.
// ---------------------------------------------------------------------------
__global__ __launch_bounds__(256) void k_rowgemm(
    const float* __restrict__ xrow, const float* __restrict__ W,
    const float* __restrict__ bias, float* __restrict__ y) {
  int b = blockIdx.x;
  int t = threadIdx.x;
  __shared__ float xs[512];
  xs[t] = xrow[b * 512 + t];
  xs[t + 256] = xrow[b * 512 + t + 256];
  __syncthreads();
  float a0 = bias[t], a1 = bias[t + 256];
  for (int kk = 0; kk < 512; kk++) {
    float xv = xs[kk];
    a0 += xv * W[(size_t)kk * 512 + t];
    a1 += xv * W[(size_t)kk * 512 + t + 256];
  }
  y[b * 512 + t] = a0;
  y[b * 512 + t + 256] = a1;
}

// ---------------------------------------------------------------------------
// Head MLP: y = relu(LN(ctx @ hW1[nh] + hb1)) ; out = y . hW2[nh] + hb2
// grid 12 = b*3 + nh
// ---------------------------------------------------------------------------
__global__ __launch_bounds__(256) void k_head(
    const float* __restrict__ ctx, const float* __restrict__ hW1,
    const float* __restrict__ hb1, const float* __restrict__ hg,
    const float* __restrict__ hbt, const float* __restrict__ hW2,
    const float* __restrict__ hb2, float* __restrict__ out) {
  int b = blockIdx.x / 3, nh = blockIdx.x % 3;
  int t = threadIdx.x;
  __shared__ float cs[512];
  __shared__ float red[4];
  cs[t] = ctx[b * 512 + t];
  cs[t + 256] = ctx[b * 512 + t + 256];
  __syncthreads();
  float y = hb1[nh * 256 + t];
  for (int d = 0; d < 512; d++) y += cs[d] * hW1[((size_t)nh * 512 + d) * 256 + t];
  float mean = block_sum(y, red) * (1.f / 256.f);
  float dv = y - mean;
  float var = block_sum(dv * dv, red) * (1.f / 256.f);
  float rs = rsqrtf(var + 1e-5f);
  float yn = dv * rs * hg[nh * 256 + t] + hbt[nh * 256 + t];
  yn = fmaxf(yn, 0.f);
  float s = block_sum(yn * hW2[nh * 256 + t], red);
  if (t == 0) out[b * 3 + nh] = s + hb2[nh];
}

// ---------------------------------------------------------------------------
extern "C" void kernel_launch(void* const* d_in, const int* in_sizes, int n_in,
                              void* d_out, int out_size, void* d_ws, size_t ws_size,
                              hipStream_t stream) {
  const float* x = (const float*)d_in[0];
  const float* in_W = (const float*)d_in[1];
  const float* in_b = (const float*)d_in[2];
  const float* in_lng = (const float*)d_in[3];
  const float* in_lnb = (const float*)d_in[4];
  const float* ln1_g = (const float*)d_in[5];
  const float* ln1_b = (const float*)d_in[6];
  const float* Wq = (const float*)d_in[7];
  const float* bq = (const float*)d_in[8];
  const float* Wk = (const float*)d_in[9];
  const float* bk = (const float*)d_in[10];
  const float* Wv = (const float*)d_in[11];
  const float* bv = (const float*)d_in[12];
  const float* Wo = (const float*)d_in[13];
  const float* bo = (const float*)d_in[14];
  const float* rel = (const float*)d_in[15];
  const float* ln2_g = (const float*)d_in[16];
  const float* ln2_b = (const float*)d_in[17];
  const float* W1 = (const float*)d_in[18];
  const float* b1 = (const float*)d_in[19];
  const float* W2 = (const float*)d_in[20];
  const float* b2 = (const float*)d_in[21];
  const float* gWq = (const float*)d_in[22];
  const float* gbq = (const float*)d_in[23];
  const float* gWk = (const float*)d_in[24];
  const float* gbk = (const float*)d_in[25];
  const float* gWv = (const float*)d_in[26];
  const float* gbv = (const float*)d_in[27];
  const float* gWo = (const float*)d_in[28];
  const float* gbo = (const float*)d_in[29];
  const float* hW1 = (const float*)d_in[30];
  const float* hb1 = (const float*)d_in[31];
  const float* hlng = (const float*)d_in[32];
  const float* hlnb = (const float*)d_in[33];
  const float* hW2 = (const float*)d_in[34];
  const float* hb2 = (const float*)d_in[35];
  float* out = (float*)d_out;

  float* ws = (float*)d_ws;
  float* h = ws;                       // 2M floats
  float* xn = ws + (size_t)BSD;        // 2M
  float* q = ws + (size_t)2 * BSD;     // 2M
  float* kk = ws + (size_t)3 * BSD;    // 2M
  float* vv = ws + (size_t)4 * BSD;    // 2M
  float* ao = ws + (size_t)5 * BSD;    // 2M
  float* ff = q;                       // reuse q..ao region: 4*BSD = B*S*FF
  float* attnlast = ws + (size_t)6 * BSD;
  float* ctx = attnlast + 4096;
  // total: 6*BSD + 8K floats ~ 50.4 MB of workspace

  k_inproj<<<4096, 256, 0, stream>>>(x, in_W, in_b, in_lng, in_lnb, h);

  for (int l = 0; l < 4; l++) {
    size_t wo = (size_t)l * 512 * 512;
    size_t vo = (size_t)l * 512;
    k_ln<<<4096, 256, 0, stream>>>(h, ln1_g + vo, ln1_b + vo, xn);
    k_gemm<0><<<dim3(8, 32), 256, 0, stream>>>(xn, Wq + wo, bq + vo, q, 512, 512);
    k_gemm<0><<<dim3(8, 32), 256, 0, stream>>>(xn, Wk + wo, bk + vo, kk, 512, 512);
    k_gemm<0><<<dim3(8, 32), 256, 0, stream>>>(xn, Wv + wo, bv + vo, vv, 512, 512);
    k_attn<<<dim3(64, 8, 4), 256, 0, stream>>>(q, kk, vv, rel + (size_t)l * 65 * 64, ao);
    k_gemm<1><<<dim3(8, 32), 256, 0, stream>>>(ao, Wo + wo, bo + vo, h, 512, 512);
    k_ln<<<4096, 256, 0, stream>>>(h, ln2_g + vo, ln2_b + vo, xn);
    k_gemm<2><<<dim3(32, 32), 256, 0, stream>>>(xn, W1 + (size_t)l * 512 * 2048,
                                                b1 + (size_t)l * 2048, ff, 2048, 512);
    k_gemm<1><<<dim3(8, 32), 256, 0, stream>>>(ff, W2 + (size_t)l * 2048 * 512,
                                               b2 + vo, h, 512, 2048);
  }

  // final global attention (only last-token query matters downstream)
  k_gemm<0><<<dim3(8, 32), 256, 0, stream>>>(h, gWq, gbq, q, 512, 512);
  k_gemm<0><<<dim3(8, 32), 256, 0, stream>>>(h, gWk, gbk, kk, 512, 512);
  k_gemm<0><<<dim3(8, 32), 256, 0, stream>>>(h, gWv, gbv, vv, 512, 512);
  k_gattn<<<32, 256, 0, stream>>>(q, kk, vv, attnlast);
  k_rowgemm<<<4, 256, 0, stream>>>(attnlast, gWo, gbo, ctx);
  k_head<<<12, 256, 0, stream>>>(ctx, hW1, hb1, hlng, hlnb, hW2, hb2, out);
}

// Round 2
// 1089.615 us; speedup vs baseline: 4.9574x; 4.9574x over previous
//
#include <hip/hip_runtime.h>
#include <math.h>

#define DEV __device__ __forceinline__

// B=4, S=1024, F=20, D=512, H=8, L=4, FF=2048, M=32, NH=3, D2=256, O=1, HD=64
constexpr int BSD = 4 * 1024 * 512;  // B*S*D

typedef __attribute__((ext_vector_type(8))) short bf16x8;
typedef __attribute__((ext_vector_type(4))) float f32x4;

DEV ushort f2b(float f) {
  union { float f; uint u; } x{f};
  uint r = x.u + 0x7fff + ((x.u >> 16) & 1);
  return (ushort)(r >> 16);
}
DEV float b2f(ushort u) {
  union { uint u; float f; } x{(uint)u << 16};
  return x.f;
}

DEV float wave_sum(float v) {
#pragma unroll
  for (int m = 32; m >= 1; m >>= 1) v += __shfl_xor(v, m, 64);
  return v;
}
DEV float wave_max(float v) {
#pragma unroll
  for (int m = 32; m >= 1; m >>= 1) v = fmaxf(v, __shfl_xor(v, m, 64));
  return v;
}
DEV float block_sum(float v, float* sm) {
  v = wave_sum(v);
  __syncthreads();
  if ((threadIdx.x & 63) == 0) sm[threadIdx.x >> 6] = v;
  __syncthreads();
  return sm[0] + sm[1] + sm[2] + sm[3];
}
DEV float block_max(float v, float* sm) {
  v = wave_max(v);
  __syncthreads();
  if ((threadIdx.x & 63) == 0) sm[threadIdx.x >> 6] = v;
  __syncthreads();
  return fmaxf(fmaxf(sm[0], sm[1]), fmaxf(sm[2], sm[3]));
}

// ---------------------------------------------------------------------------
// Input projection (fp32 h): h = LN(x @ in_W + in_b)*g + b + posenc
// ---------------------------------------------------------------------------
__global__ __launch_bounds__(256) void k_inproj(
    const float* __restrict__ x, const float* __restrict__ W,
    const float* __restrict__ bias, const float* __restrict__ g,
    const float* __restrict__ bt, float* __restrict__ h) {
  int r = blockIdx.x;
  int s = r & 1023;
  int t = threadIdx.x;
  __shared__ float xr[20];
  __shared__ float red[4];
  if (t < 20) xr[t] = x[r * 20 + t];
  __syncthreads();
  float o0 = bias[t], o1 = bias[t + 256];
#pragma unroll
  for (int f = 0; f < 20; f++) {
    float xv = xr[f];
    o0 += xv * W[f * 512 + t];
    o1 += xv * W[f * 512 + t + 256];
  }
  float mean = block_sum(o0 + o1, red) * (1.f / 512.f);
  float d0 = o0 - mean, d1 = o1 - mean;
  float var = block_sum(d0 * d0 + d1 * d1, red) * (1.f / 512.f);
  float rs = rsqrtf(var + 1e-5f);
  float n0 = d0 * rs * g[t] + bt[t];
  float n1 = d1 * rs * g[t + 256] + bt[t + 256];
  const float c1 = -9.210340371976184f / 512.f;
  {
    int c = t;
    float div = expf((float)(c & ~1) * c1);
    float arg = (float)s * div;
    n0 += (c & 1) ? cosf(arg) : sinf(arg);
  }
  {
    int c = t + 256;
    float div = expf((float)(c & ~1) * c1);
    float arg = (float)s * div;
    n1 += (c & 1) ? cosf(arg) : sinf(arg);
  }
  float* hr = h + (size_t)r * 512;
  hr[t] = n0;
  hr[t + 256] = n1;
}

// ---------------------------------------------------------------------------
// LayerNorm fp32 -> bf16 out
// ---------------------------------------------------------------------------
__global__ __launch_bounds__(256) void k_lnb(
    const float* __restrict__ x, const float* __restrict__ g,
    const float* __restrict__ bt, ushort* __restrict__ y) {
  __shared__ float red[4];
  int r = blockIdx.x;
  int t = threadIdx.x;
  const float* xr = x + (size_t)r * 512;
  float v0 = xr[t], v1 = xr[t + 256];
  float mean = block_sum(v0 + v1, red) * (1.f / 512.f);
  float d0 = v0 - mean, d1 = v1 - mean;
  float var = block_sum(d0 * d0 + d1 * d1, red) * (1.f / 512.f);
  float rs = rsqrtf(var + 1e-5f);
  ushort* yr = y + (size_t)r * 512;
  yr[t] = f2b(d0 * rs * g[t] + bt[t]);
  yr[t + 256] = f2b(d1 * rs * g[t + 256] + bt[t + 256]);
}

// fp32 -> bf16 plain convert
__global__ __launch_bounds__(256) void k_cvt(const float* __restrict__ x,
                                             ushort* __restrict__ y) {
  int i = blockIdx.x * 256 + threadIdx.x;
  y[i] = f2b(x[i]);
}

// ---------------------------------------------------------------------------
// Weight prep: transpose+convert src[K][N] f32 -> dst[N][K] bf16 (up to 4 via z)
// ---------------------------------------------------------------------------
__global__ __launch_bounds__(256) void k_wprep4(
    const float* s0, const float* s1, const float* s2, const float* s3,
    ushort* d0, ushort* d1, ushort* d2, ushort* d3, int K, int N) {
  const float* src;
  ushort* dst;
  switch (blockIdx.z) {
    case 0: src = s0; dst = d0; break;
    case 1: src = s1; dst = d1; break;
    case 2: src = s2; dst = d2; break;
    default: src = s3; dst = d3; break;
  }
  __shared__ float ld[32][33];
  int n0 = blockIdx.x * 32, k0 = blockIdx.y * 32;
  int c = threadIdx.x & 31, r0 = threadIdx.x >> 5;
#pragma unroll
  for (int i = 0; i < 4; i++)
    ld[r0 + i * 8][c] = src[(size_t)(k0 + r0 + i * 8) * N + n0 + c];
  __syncthreads();
#pragma unroll
  for (int i = 0; i < 4; i++)
    dst[(size_t)(n0 + r0 + i * 8) * K + k0 + c] = f2b(ld[c][r0 + i * 8]);
}

// rel [L][65][64] f32 -> [L][80][64] bf16, zero-padded rows 65..79
__global__ __launch_bounds__(256) void k_relprep(const float* __restrict__ rel,
                                                 ushort* __restrict__ relb) {
  int i = blockIdx.x * 256 + threadIdx.x;  // 0..5119
  int l = blockIdx.y;
  int r = i >> 6, d = i & 63;
  float v = (r < 65) ? rel[((size_t)l * 65 + r) * 64 + d] : 0.f;
  relb[(size_t)l * 80 * 64 + i] = f2b(v);
}

// ---------------------------------------------------------------------------
// bf16 MFMA GEMM: C(MxN) = A[M][K]bf16 @ Bt[N][K]bf16^T + bias
// BM=128, BN in {64,128}, BK=64, 256 threads (4 waves).
// MODE 0: bf16 out; MODE 1: fp32 residual in-place; MODE 2: gelu -> bf16
// ---------------------------------------------------------------------------
template <int BN, int MODE>
__global__ __launch_bounds__(256) void k_mgemm(
    const ushort* __restrict__ A, const ushort* __restrict__ Bt,
    const float* __restrict__ bias, void* __restrict__ Cv, int N, int K) {
  constexpr int BM = 128, BK = 64, LDT = BK + 8;  // 72
  __shared__ __align__(16) ushort As[BM * LDT];
  __shared__ __align__(16) ushort Bs[BN * LDT];
  int t = threadIdx.x;
  int lane = t & 63, w = t >> 6;
  int rl15 = lane & 15, l16 = lane >> 4;
  int row0 = blockIdx.y * BM, col0 = blockIdx.x * BN;
  constexpr int WCOLS = (BN == 128) ? 2 : 1;
  constexpr int MI = (BN == 128) ? 4 : 2;
  constexpr int NI = 4;
  int wr = w / WCOLS, wc = w % WCOLS;
  int wrow = wr * MI * 16;
  int wcol = wc * 64;
  f32x4 acc[MI][NI] = {};
  constexpr int ACH = (BM * BK) / (256 * 8);
  constexpr int BCH = (BN * BK) / (256 * 8);
  for (int kb = 0; kb < K; kb += BK) {
    __syncthreads();
#pragma unroll
    for (int i = 0; i < ACH; i++) {
      int c = t + i * 256;
      int r = c >> 3, cb = c & 7;
      bf16x8 v8 = *(const bf16x8*)(A + (size_t)(row0 + r) * K + kb + cb * 8);
      *(bf16x8*)&As[r * LDT + cb * 8] = v8;
    }
#pragma unroll
    for (int i = 0; i < BCH; i++) {
      int c = t + i * 256;
      int r = c >> 3, cb = c & 7;
      bf16x8 v8 = *(const bf16x8*)(Bt + (size_t)(col0 + r) * K + kb + cb * 8);
      *(bf16x8*)&Bs[r * LDT + cb * 8] = v8;
    }
    __syncthreads();
#pragma unroll
    for (int ks = 0; ks < 2; ks++) {
      bf16x8 af[MI], bfr[NI];
#pragma unroll
      for (int mi = 0; mi < MI; mi++)
        af[mi] = *(const bf16x8*)&As[(wrow + mi * 16 + rl15) * LDT + ks * 32 + l16 * 8];
#pragma unroll
      for (int ni = 0; ni < NI; ni++)
        bfr[ni] = *(const bf16x8*)&Bs[(wcol + ni * 16 + rl15) * LDT + ks * 32 + l16 * 8];
#pragma unroll
      for (int mi = 0; mi < MI; mi++)
#pragma unroll
        for (int ni = 0; ni < NI; ni++)
          acc[mi][ni] = __builtin_amdgcn_mfma_f32_16x16x32_bf16(af[mi], bfr[ni],
                                                                acc[mi][ni], 0, 0, 0);
    }
  }
#pragma unroll
  for (int mi = 0; mi < MI; mi++) {
#pragma unroll
    for (int ni = 0; ni < NI; ni++) {
      int col = col0 + wcol + ni * 16 + rl15;
      float bv = bias[col];
#pragma unroll
      for (int r = 0; r < 4; r++) {
        int row = row0 + wrow + mi * 16 + l16 * 4 + r;
        float val = acc[mi][ni][r] + bv;
        if (MODE == 0) {
          ((ushort*)Cv)[(size_t)row * N + col] = f2b(val);
        } else if (MODE == 1) {
          float* Cp = (float*)Cv + (size_t)row * N + col;
          *Cp = *Cp + val;
        } else {
          val = 0.5f * val * (1.f + erff(val * 0.70710678118654752f));
          ((ushort*)Cv)[(size_t)row * N + col] = f2b(val);
        }
      }
    }
  }
}

// ---------------------------------------------------------------------------
// MFMA flash attention with relative positions, bf16 in/out, fp32 softmax.
// grid (S/64, H, B), 256 threads = 4 waves; wave owns 16 q-rows.
// ---------------------------------------------------------------------------
__global__ __launch_bounds__(256) void k_attn_mfma(
    const ushort* __restrict__ q, const ushort* __restrict__ k,
    const ushort* __restrict__ v, const ushort* __restrict__ relb,
    ushort* __restrict__ ao) {
  __shared__ __align__(16) ushort Ks[64 * 72];
  __shared__ __align__(16) ushort Vt[64 * 72];
  __shared__ float qrl[64][66];
  __shared__ __align__(16) ushort Pl[4][16 * 72];
  int t = threadIdx.x, lane = t & 63, w = t >> 6;
  int h = blockIdx.y, b = blockIdx.z;
  int q0 = blockIdx.x * 64;
  size_t base = ((size_t)b * 1024) * 512 + h * 64;
  int qw = q0 + w * 16;
  int rl15 = lane & 15, l16 = lane >> 4;

  // Q fragments (held in regs for the whole kernel)
  bf16x8 aq[2];
#pragma unroll
  for (int ks = 0; ks < 2; ks++)
    aq[ks] = *(const bf16x8*)(q + base + (size_t)(qw + rl15) * 512 + ks * 32 + l16 * 8);

  // qrel[qrow][r] = Q . rel[r]  via MFMA (B-frags streamed from global relb)
#pragma unroll
  for (int nb = 0; nb < 5; nb++) {
    f32x4 rc = {};
#pragma unroll
    for (int ks = 0; ks < 2; ks++) {
      bf16x8 rb = *(const bf16x8*)(relb + (size_t)(nb * 16 + rl15) * 64 + ks * 32 + l16 * 8);
      rc = __builtin_amdgcn_mfma_f32_16x16x32_bf16(aq[ks], rb, rc, 0, 0, 0);
    }
    int col = nb * 16 + rl15;
    if (col < 65) {
#pragma unroll
      for (int r = 0; r < 4; r++) qrl[w * 16 + l16 * 4 + r][col] = rc[r];
    }
  }

  float mrow[4], lrow[4];
  f32x4 oacc[4] = {};
#pragma unroll
  for (int r = 0; r < 4; r++) {
    mrow[r] = -1e30f;
    lrow[r] = 0.f;
  }

  for (int kb = 0; kb < 1024; kb += 64) {
    __syncthreads();
    // stage K tile [64 keys][64 d]
#pragma unroll
    for (int i = 0; i < 2; i++) {
      int c = t + i * 256;
      int key = c >> 3, dc = c & 7;
      bf16x8 kv = *(const bf16x8*)(k + base + (size_t)(kb + key) * 512 + dc * 8);
      *(bf16x8*)&Ks[key * 72 + dc * 8] = kv;
    }
    // stage V transposed: Vt[d][key]
#pragma unroll
    for (int i = 0; i < 2; i++) {
      int c = t + i * 256;
      int key = c & 63, dh = c >> 6;
      bf16x8 vv8 = *(const bf16x8*)(v + base + (size_t)(kb + key) * 512 + dh * 8);
#pragma unroll
      for (int e = 0; e < 8; e++) Vt[(dh * 8 + e) * 72 + key] = (ushort)vv8[e];
    }
    __syncthreads();

    // S = Q K^T
    f32x4 sacc[4] = {};
#pragma unroll
    for (int ks = 0; ks < 2; ks++) {
#pragma unroll
      for (int nb = 0; nb < 4; nb++) {
        bf16x8 bk8 = *(const bf16x8*)&Ks[(nb * 16 + rl15) * 72 + ks * 32 + l16 * 8];
        sacc[nb] = __builtin_amdgcn_mfma_f32_16x16x32_bf16(aq[ks], bk8, sacc[nb], 0, 0, 0);
      }
    }

    // rel add + online softmax (rows live on 16 consecutive lanes)
    float p[4][4];
#pragma unroll
    for (int r = 0; r < 4; r++) {
      int rloc = l16 * 4 + r;
      int qg = q0 + w * 16 + rloc;
      float sv[4];
      float rowm = -1e30f;
#pragma unroll
      for (int nb = 0; nb < 4; nb++) {
        int kcol = kb + nb * 16 + rl15;
        int delta = kcol - qg;
        delta = delta < -32 ? -32 : (delta > 32 ? 32 : delta);
        float s_ = sacc[nb][r] * 0.125f + qrl[w * 16 + rloc][delta + 32];
        sv[nb] = s_;
        rowm = fmaxf(rowm, s_);
      }
#pragma unroll
      for (int msk = 1; msk <= 8; msk <<= 1)
        rowm = fmaxf(rowm, __shfl_xor(rowm, msk, 64));
      float mn = fmaxf(mrow[r], rowm);
      float scale = __expf(mrow[r] - mn);
      float ls = 0.f;
#pragma unroll
      for (int nb = 0; nb < 4; nb++) {
        float pv = __expf(sv[nb] - mn);
        p[nb][r] = pv;
        ls += pv;
      }
#pragma unroll
      for (int msk = 1; msk <= 8; msk <<= 1) ls += __shfl_xor(ls, msk, 64);
      lrow[r] = lrow[r] * scale + ls;
      mrow[r] = mn;
#pragma unroll
      for (int nb = 0; nb < 4; nb++) oacc[nb][r] *= scale;
    }

    // P -> wave-private LDS (C-layout), re-read as A-frags
#pragma unroll
    for (int nb = 0; nb < 4; nb++)
#pragma unroll
      for (int r = 0; r < 4; r++)
        Pl[w][(l16 * 4 + r) * 72 + nb * 16 + rl15] = f2b(p[nb][r]);
#pragma unroll
    for (int ks = 0; ks < 2; ks++) {
      bf16x8 pa = *(const bf16x8*)&Pl[w][rl15 * 72 + ks * 32 + l16 * 8];
#pragma unroll
      for (int nb = 0; nb < 4; nb++) {
        bf16x8 bv8 = *(const bf16x8*)&Vt[(nb * 16 + rl15) * 72 + ks * 32 + l16 * 8];
        oacc[nb] = __builtin_amdgcn_mfma_f32_16x16x32_bf16(pa, bv8, oacc[nb], 0, 0, 0);
      }
    }
  }

#pragma unroll
  for (int nb = 0; nb < 4; nb++) {
    int d = nb * 16 + rl15;
#pragma unroll
    for (int r = 0; r < 4; r++) {
      int row = q0 + w * 16 + l16 * 4 + r;
      ao[base + (size_t)row * 512 + d] = f2b(oacc[nb][r] / lrow[r]);
    }
  }
}

// ---------------------------------------------------------------------------
// Final global attention (bf16 q/k/v, fp32 out), last query row only.
// ---------------------------------------------------------------------------
__global__ __launch_bounds__(256) void k_gattn(
    const ushort* __restrict__ q, const ushort* __restrict__ k,
    const ushort* __restrict__ v, float* __restrict__ ctxa) {
  int t = threadIdx.x;
  int h = blockIdx.x & 7, b = blockIdx.x >> 3;
  __shared__ float Qs[64];
  __shared__ float sc[1024];
  __shared__ float red[4];
  __shared__ float op[4][64];
  if (t < 64) Qs[t] = b2f(q[(size_t)(b * 1024 + 1023) * 512 + h * 64 + t]);
  __syncthreads();
  float lm = -1e30f;
  float sv[4];
#pragma unroll
  for (int jj = 0; jj < 4; jj++) {
    int j = t + (jj << 8);
    float s = 0.f;
#pragma unroll
    for (int d = 0; d < 64; d++)
      s += Qs[d] * b2f(k[(size_t)(b * 1024 + j) * 512 + h * 64 + d]);
    s *= 0.125f;
    sv[jj] = s;
    lm = fmaxf(lm, s);
  }
  float bm = block_max(lm, red);
  float ls = 0.f;
#pragma unroll
  for (int jj = 0; jj < 4; jj++) {
    float e = __expf(sv[jj] - bm);
    sc[t + (jj << 8)] = e;
    ls += e;
  }
  float bs = block_sum(ls, red);
  int d = t & 63, qd = t >> 6;
  float acc = 0.f;
  for (int j = qd << 8; j < (qd << 8) + 256; j++)
    acc += sc[j] * b2f(v[(size_t)(b * 1024 + j) * 512 + h * 64 + d]);
  op[qd][d] = acc;
  __syncthreads();
  if (t < 64) {
    float r = (op[0][t] + op[1][t] + op[2][t] + op[3][t]) / bs;
    ctxa[b * 512 + h * 64 + t] = r;
  }
}

// ---------------------------------------------------------------------------
// 4-row GEMM (fp32): ctx = attnlast @ gWo + gbo
// ---------------------------------------------------------------------------
__global__ __launch_bounds__(256) void k_rowgemm(
    const float* __restrict__ xrow, const float* __restrict__ W,
    const float* __restrict__ bias, float* __restrict__ y) {
  int b = blockIdx.x;
  int t = threadIdx.x;
  __shared__ float xs[512];
  xs[t] = xrow[b * 512 + t];
  xs[t + 256] = xrow[b * 512 + t + 256];
  __syncthreads();
  float a0 = bias[t], a1 = bias[t + 256];
  for (int kk = 0; kk < 512; kk++) {
    float xv = xs[kk];
    a0 += xv * W[(size_t)kk * 512 + t];
    a1 += xv * W[(size_t)kk * 512 + t + 256];
  }
  y[b * 512 + t] = a0;
  y[b * 512 + t + 256] = a1;
}

// ---------------------------------------------------------------------------
// Head MLP (fp32)
// ---------------------------------------------------------------------------
__global__ __launch_bounds__(256) void k_head(
    const float* __restrict__ ctx, const float* __restrict__ hW1,
    const float* __restrict__ hb1, const float* __restrict__ hg,
    const float* __restrict__ hbt, const float* __restrict__ hW2,
    const float* __restrict__ hb2, float* __restrict__ out) {
  int b = blockIdx.x / 3, nh = blockIdx.x % 3;
  int t = threadIdx.x;
  __shared__ float cs[512];
  __shared__ float red[4];
  cs[t] = ctx[b * 512 + t];
  cs[t + 256] = ctx[b * 512 + t + 256];
  __syncthreads();
  float y = hb1[nh * 256 + t];
  for (int d = 0; d < 512; d++) y += cs[d] * hW1[((size_t)nh * 512 + d) * 256 + t];
  float mean = block_sum(y, red) * (1.f / 256.f);
  float dv = y - mean;
  float var = block_sum(dv * dv, red) * (1.f / 256.f);
  float rs = rsqrtf(var + 1e-5f);
  float yn = dv * rs * hg[nh * 256 + t] + hbt[nh * 256 + t];
  yn = fmaxf(yn, 0.f);
  float s = block_sum(yn * hW2[nh * 256 + t], red);
  if (t == 0) out[b * 3 + nh] = s + hb2[nh];
}

// ---------------------------------------------------------------------------
extern "C" void kernel_launch(void* const* d_in, const int* in_sizes, int n_in,
                              void* d_out, int out_size, void* d_ws, size_t ws_size,
                              hipStream_t stream) {
  const float* x = (const float*)d_in[0];
  const float* in_W = (const float*)d_in[1];
  const float* in_b = (const float*)d_in[2];
  const float* in_lng = (const float*)d_in[3];
  const float* in_lnb = (const float*)d_in[4];
  const float* ln1_g = (const float*)d_in[5];
  const float* ln1_b = (const float*)d_in[6];
  const float* Wq = (const float*)d_in[7];
  const float* bq = (const float*)d_in[8];
  const float* Wk = (const float*)d_in[9];
  const float* bk = (const float*)d_in[10];
  const float* Wv = (const float*)d_in[11];
  const float* bv = (const float*)d_in[12];
  const float* Wo = (const float*)d_in[13];
  const float* bo = (const float*)d_in[14];
  const float* rel = (const float*)d_in[15];
  const float* ln2_g = (const float*)d_in[16];
  const float* ln2_b = (const float*)d_in[17];
  const float* W1 = (const float*)d_in[18];
  const float* b1 = (const float*)d_in[19];
  const float* W2 = (const float*)d_in[20];
  const float* b2 = (const float*)d_in[21];
  const float* gWq = (const float*)d_in[22];
  const float* gbq = (const float*)d_in[23];
  const float* gWk = (const float*)d_in[24];
  const float* gbk = (const float*)d_in[25];
  const float* gWv = (const float*)d_in[26];
  const float* gbv = (const float*)d_in[27];
  const float* gWo = (const float*)d_in[28];
  const float* gbo = (const float*)d_in[29];
  const float* hW1 = (const float*)d_in[30];
  const float* hb1 = (const float*)d_in[31];
  const float* hlng = (const float*)d_in[32];
  const float* hlnb = (const float*)d_in[33];
  const float* hW2 = (const float*)d_in[34];
  const float* hb2 = (const float*)d_in[35];
  float* out = (float*)d_out;

  uint8_t* wsb = (uint8_t*)d_ws;
  const size_t MB = 1024 * 1024;
  float* h = (float*)(wsb + 0);            // 8 MB
  ushort* xn = (ushort*)(wsb + 8 * MB);    // 4 MB
  ushort* qb = (ushort*)(wsb + 12 * MB);   // 4 MB
  ushort* kb = (ushort*)(wsb + 16 * MB);   // 4 MB
  ushort* vb = (ushort*)(wsb + 20 * MB);   // 4 MB
  ushort* aob = (ushort*)(wsb + 24 * MB);  // 4 MB
  ushort* ffb = qb;                        // 16 MB spanning qb..aob
  ushort* wtq = (ushort*)(wsb + 28 * MB);         // 0.5 MB each
  ushort* wtk = (ushort*)(wsb + 28 * MB + 524288);
  ushort* wtv = (ushort*)(wsb + 29 * MB);
  ushort* wto = (ushort*)(wsb + 29 * MB + 524288);
  ushort* wt1 = (ushort*)(wsb + 30 * MB);  // 2 MB
  ushort* wt2 = (ushort*)(wsb + 32 * MB);  // 2 MB
  ushort* relb = (ushort*)(wsb + 34 * MB); // 40 KB
  float* attnlast = (float*)(wsb + 34 * MB + 65536);
  float* ctx = attnlast + 4096;

  k_inproj<<<4096, 256, 0, stream>>>(x, in_W, in_b, in_lng, in_lnb, h);
  k_relprep<<<dim3(20, 4), 256, 0, stream>>>(rel, relb);

  for (int l = 0; l < 4; l++) {
    size_t wo = (size_t)l * 512 * 512;
    size_t vo = (size_t)l * 512;
    k_wprep4<<<dim3(16, 16, 4), 256, 0, stream>>>(Wq + wo, Wk + wo, Wv + wo, Wo + wo,
                                                  wtq, wtk, wtv, wto, 512, 512);
    k_wprep4<<<dim3(64, 16, 1), 256, 0, stream>>>(W1 + (size_t)l * 512 * 2048, 0, 0, 0,
                                                  wt1, 0, 0, 0, 512, 2048);
    k_wprep4<<<dim3(16, 64, 1), 256, 0, stream>>>(W2 + (size_t)l * 2048 * 512, 0, 0, 0,
                                                  wt2, 0, 0, 0, 2048, 512);
    k_lnb<<<4096, 256, 0, stream>>>(h, ln1_g + vo, ln1_b + vo, xn);
    k_mgemm<64, 0><<<dim3(8, 32), 256, 0, stream>>>(xn, wtq, bq + vo, qb, 512, 512);
    k_mgemm<64, 0><<<dim3(8, 32), 256, 0, stream>>>(xn, wtk, bk + vo, kb, 512, 512);
    k_mgemm<64, 0><<<dim3(8, 32), 256, 0, stream>>>(xn, wtv, bv + vo, vb, 512, 512);
    k_attn_mfma<<<dim3(16, 8, 4), 256, 0, stream>>>(qb, kb, vb, relb + (size_t)l * 80 * 64, aob);
    k_mgemm<64, 1><<<dim3(8, 32), 256, 0, stream>>>(aob, wto, bo + vo, h, 512, 512);
    k_lnb<<<4096, 256, 0, stream>>>(h, ln2_g + vo, ln2_b + vo, xn);
    k_mgemm<128, 2><<<dim3(16, 32), 256, 0, stream>>>(xn, wt1, b1 + (size_t)l * 2048,
                                                      ffb, 2048, 512);
    k_mgemm<64, 1><<<dim3(8, 32), 256, 0, stream>>>(ffb, wt2, b2 + vo, h, 512, 2048);
  }

  // final global attention
  k_cvt<<<8192, 256, 0, stream>>>(h, xn);
  k_wprep4<<<dim3(16, 16, 3), 256, 0, stream>>>(gWq, gWk, gWv, gWv, wtq, wtk, wtv, wtv,
                                                512, 512);
  k_mgemm<64, 0><<<dim3(8, 32), 256, 0, stream>>>(xn, wtq, gbq, qb, 512, 512);
  k_mgemm<64, 0><<<dim3(8, 32), 256, 0, stream>>>(xn, wtk, gbk, kb, 512, 512);
  k_mgemm<64, 0><<<dim3(8, 32), 256, 0, stream>>>(xn, wtv, gbv, vb, 512, 512);
  k_gattn<<<32, 256, 0, stream>>>(qb, kb, vb, attnlast);
  k_rowgemm<<<4, 256, 0, stream>>>(attnlast, gWo, gbo, ctx);
  k_head<<<12, 256, 0, stream>>>(ctx, hW1, hb1, hlng, hlnb, hW2, hb2, out);
}

// Round 3
// 631.206 us; speedup vs baseline: 8.5577x; 1.7262x over previous
//
#include <hip/hip_runtime.h>
#include <math.h>

#define DEV __device__ __forceinline__

// B=4, S=1024, F=20, D=512, H=8, L=4, FF=2048, M=32, NH=3, D2=256, O=1, HD=64
constexpr int BSD = 4 * 1024 * 512;  // B*S*D

typedef __attribute__((ext_vector_type(8))) short bf16x8;
typedef __attribute__((ext_vector_type(4))) float f32x4;

typedef __attribute__((address_space(1))) const void global_cvoid;
typedef __attribute__((address_space(3))) void lds_void;

DEV ushort f2b(float f) {
  union { float f; uint u; } x{f};
  uint r = x.u + 0x7fff + ((x.u >> 16) & 1);
  return (ushort)(r >> 16);
}
DEV float b2f(ushort u) {
  union { uint u; float f; } x{(uint)u << 16};
  return x.f;
}
DEV int swz128(int b) { return b ^ (((b >> 7) & 7) << 4); }

DEV float wave_sum(float v) {
#pragma unroll
  for (int m = 32; m >= 1; m >>= 1) v += __shfl_xor(v, m, 64);
  return v;
}
DEV float wave_max(float v) {
#pragma unroll
  for (int m = 32; m >= 1; m >>= 1) v = fmaxf(v, __shfl_xor(v, m, 64));
  return v;
}
DEV float block_sum(float v, float* sm) {
  v = wave_sum(v);
  __syncthreads();
  if ((threadIdx.x & 63) == 0) sm[threadIdx.x >> 6] = v;
  __syncthreads();
  return sm[0] + sm[1] + sm[2] + sm[3];
}
DEV float block_max(float v, float* sm) {
  v = wave_max(v);
  __syncthreads();
  if ((threadIdx.x & 63) == 0) sm[threadIdx.x >> 6] = v;
  __syncthreads();
  return fmaxf(fmaxf(sm[0], sm[1]), fmaxf(sm[2], sm[3]));
}

// ---------------------------------------------------------------------------
// Input projection (fp32 h): h = LN(x @ in_W + in_b)*g + b + posenc
// ---------------------------------------------------------------------------
__global__ __launch_bounds__(256) void k_inproj(
    const float* __restrict__ x, const float* __restrict__ W,
    const float* __restrict__ bias, const float* __restrict__ g,
    const float* __restrict__ bt, float* __restrict__ h) {
  int r = blockIdx.x;
  int s = r & 1023;
  int t = threadIdx.x;
  __shared__ float xr[20];
  __shared__ float red[4];
  if (t < 20) xr[t] = x[r * 20 + t];
  __syncthreads();
  float o0 = bias[t], o1 = bias[t + 256];
#pragma unroll
  for (int f = 0; f < 20; f++) {
    float xv = xr[f];
    o0 += xv * W[f * 512 + t];
    o1 += xv * W[f * 512 + t + 256];
  }
  float mean = block_sum(o0 + o1, red) * (1.f / 512.f);
  float d0 = o0 - mean, d1 = o1 - mean;
  float var = block_sum(d0 * d0 + d1 * d1, red) * (1.f / 512.f);
  float rs = rsqrtf(var + 1e-5f);
  float n0 = d0 * rs * g[t] + bt[t];
  float n1 = d1 * rs * g[t + 256] + bt[t + 256];
  const float c1 = -9.210340371976184f / 512.f;
  {
    int c = t;
    float div = expf((float)(c & ~1) * c1);
    float arg = (float)s * div;
    n0 += (c & 1) ? cosf(arg) : sinf(arg);
  }
  {
    int c = t + 256;
    float div = expf((float)(c & ~1) * c1);
    float arg = (float)s * div;
    n1 += (c & 1) ? cosf(arg) : sinf(arg);
  }
  float* hr = h + (size_t)r * 512;
  hr[t] = n0;
  hr[t + 256] = n1;
}

// ---------------------------------------------------------------------------
// LayerNorm fp32 -> bf16 out
// ---------------------------------------------------------------------------
__global__ __launch_bounds__(256) void k_lnb(
    const float* __restrict__ x, const float* __restrict__ g,
    const float* __restrict__ bt, ushort* __restrict__ y) {
  __shared__ float red[4];
  int r = blockIdx.x;
  int t = threadIdx.x;
  const float* xr = x + (size_t)r * 512;
  float v0 = xr[t], v1 = xr[t + 256];
  float mean = block_sum(v0 + v1, red) * (1.f / 512.f);
  float d0 = v0 - mean, d1 = v1 - mean;
  float var = block_sum(d0 * d0 + d1 * d1, red) * (1.f / 512.f);
  float rs = rsqrtf(var + 1e-5f);
  ushort* yr = y + (size_t)r * 512;
  yr[t] = f2b(d0 * rs * g[t] + bt[t]);
  yr[t + 256] = f2b(d1 * rs * g[t + 256] + bt[t + 256]);
}

// fp32 -> bf16 plain convert
__global__ __launch_bounds__(256) void k_cvt(const float* __restrict__ x,
                                             ushort* __restrict__ y) {
  int i = blockIdx.x * 256 + threadIdx.x;
  y[i] = f2b(x[i]);
}

// ---------------------------------------------------------------------------
// Weight prep: transpose+convert src[K][N] f32 -> dst[N][K] bf16, job table.
// ---------------------------------------------------------------------------
struct PJobs {
  const float* s[19];
  ushort* d[19];
};
__global__ __launch_bounds__(256) void k_wprep(PJobs j, int K, int N) {
  const float* src = j.s[blockIdx.z];
  ushort* dst = j.d[blockIdx.z];
  __shared__ float ld[32][33];
  int n0 = blockIdx.x * 32, k0 = blockIdx.y * 32;
  int c = threadIdx.x & 31, r0 = threadIdx.x >> 5;
#pragma unroll
  for (int i = 0; i < 4; i++)
    ld[r0 + i * 8][c] = src[(size_t)(k0 + r0 + i * 8) * N + n0 + c];
  __syncthreads();
#pragma unroll
  for (int i = 0; i < 4; i++)
    dst[(size_t)(n0 + r0 + i * 8) * K + k0 + c] = f2b(ld[c][r0 + i * 8]);
}

// rel [L][65][64] f32 -> [L][80][64] bf16, zero-padded rows 65..79
__global__ __launch_bounds__(256) void k_relprep(const float* __restrict__ rel,
                                                 ushort* __restrict__ relb) {
  int i = blockIdx.x * 256 + threadIdx.x;  // 0..5119
  int l = blockIdx.y;
  int r = i >> 6, d = i & 63;
  float v = (r < 65) ? rel[((size_t)l * 65 + r) * 64 + d] : 0.f;
  relb[(size_t)l * 80 * 64 + i] = f2b(v);
}

// ---------------------------------------------------------------------------
// bf16 MFMA GEMM, m97-style: global_load_lds(16B) -> linear LDS with
// source-side XOR swizzle; XCD-chunked 1D grid; BN=64, BK=64, 4 waves.
// BM in {64,128}. MODE 0: bf16 out; 1: fp32 residual in-place; 2: gelu bf16.
// FUSEB: bias selected from 3 pointers by col/512 (fused QKV).
// ---------------------------------------------------------------------------
template <int BM, int MODE, int FUSEB>
__global__ __launch_bounds__(256) void k_mg(
    const ushort* __restrict__ A, const ushort* __restrict__ Bt,
    const float* __restrict__ bias0, const float* __restrict__ bias1,
    const float* __restrict__ bias2, void* __restrict__ Cv,
    int K, int ldc, int gx) {
  constexpr int BN = 64, BK = 64;
  __shared__ __align__(16) ushort As[BM * BK];
  __shared__ __align__(16) ushort Bs[BN * BK];
  // XCD-chunked remap (nwg % 8 == 0 for all launches)
  int nwg = gridDim.x;
  int id = blockIdx.x;
  int logical = (id & 7) * (nwg >> 3) + (id >> 3);
  int bx = logical % gx, by = logical / gx;
  int row0 = by * BM, col0 = bx * BN;
  int t = threadIdx.x, lane = t & 63, w = t >> 6;
  int rl15 = lane & 15, l16 = lane >> 4;
  constexpr int WR = BM / 32;         // waves along rows
  constexpr int WC = 4 / WR;          // waves along cols
  constexpr int NI = 64 / (WC * 16);  // 4 (BM=128) or 2 (BM=64)
  constexpr int MI = 2;
  int wr = w % WR, wc = w / WR;
  int wrow = wr * 32;
  int wcol = wc * (WC == 2 ? 32 : 0);
  f32x4 acc[MI][NI] = {};
  for (int kb = 0; kb < K; kb += BK) {
    __syncthreads();
    // stage A: BM/8 1KB-blocks, wave w owns blocks [w*BM/32, (w+1)*BM/32)
#pragma unroll
    for (int i = 0; i < BM / 32; i++) {
      int blk = w * (BM / 32) + i;
      int lb = blk * 1024 + lane * 16;     // linear LDS byte this lane fills
      int lg = swz128(lb);                 // logical byte whose data goes there
      int r = lg >> 7, cb = (lg & 127) >> 1;
      __builtin_amdgcn_global_load_lds(
          (global_cvoid*)(A + (size_t)(row0 + r) * K + kb + cb),
          (lds_void*)((char*)As + blk * 1024), 16, 0, 0);
    }
    // stage B: 8 blocks, wave w owns 2
#pragma unroll
    for (int i = 0; i < 2; i++) {
      int blk = w * 2 + i;
      int lb = blk * 1024 + lane * 16;
      int lg = swz128(lb);
      int r = lg >> 7, cb = (lg & 127) >> 1;
      __builtin_amdgcn_global_load_lds(
          (global_cvoid*)(Bt + (size_t)(col0 + r) * K + kb + cb),
          (lds_void*)((char*)Bs + blk * 1024), 16, 0, 0);
    }
    __syncthreads();
#pragma unroll
    for (int ks = 0; ks < 2; ks++) {
      bf16x8 af[MI], bfr[NI];
#pragma unroll
      for (int mi = 0; mi < MI; mi++) {
        int row = wrow + mi * 16 + rl15;
        af[mi] = *(const bf16x8*)((char*)As + swz128(row * 128 + ks * 64 + l16 * 16));
      }
#pragma unroll
      for (int ni = 0; ni < NI; ni++) {
        int row = wcol + ni * 16 + rl15;
        bfr[ni] = *(const bf16x8*)((char*)Bs + swz128(row * 128 + ks * 64 + l16 * 16));
      }
#pragma unroll
      for (int mi = 0; mi < MI; mi++)
#pragma unroll
        for (int ni = 0; ni < NI; ni++)
          acc[mi][ni] = __builtin_amdgcn_mfma_f32_16x16x32_bf16(af[mi], bfr[ni],
                                                                acc[mi][ni], 0, 0, 0);
    }
  }
#pragma unroll
  for (int mi = 0; mi < MI; mi++) {
#pragma unroll
    for (int ni = 0; ni < NI; ni++) {
      int col = col0 + wcol + ni * 16 + rl15;
      float bv;
      if (FUSEB) {
        const float* bp = bias0;
        int c = col;
        if (c >= 1024) { bp = bias2; c -= 1024; }
        else if (c >= 512) { bp = bias1; c -= 512; }
        bv = bp[c];
      } else {
        bv = bias0[col];
      }
#pragma unroll
      for (int r = 0; r < 4; r++) {
        int row = row0 + wrow + mi * 16 + l16 * 4 + r;
        float val = acc[mi][ni][r] + bv;
        if (MODE == 0) {
          ((ushort*)Cv)[(size_t)row * ldc + col] = f2b(val);
        } else if (MODE == 1) {
          float* Cp = (float*)Cv + (size_t)row * ldc + col;
          *Cp = *Cp + val;
        } else {
          val = 0.5f * val * (1.f + erff(val * 0.70710678118654752f));
          ((ushort*)Cv)[(size_t)row * ldc + col] = f2b(val);
        }
      }
    }
  }
}

// ---------------------------------------------------------------------------
// MFMA flash attention with relative positions. qkv fused layout [r][1536].
// grid (S/64, H, B), 256 threads = 4 waves; wave owns 16 q-rows.
// ---------------------------------------------------------------------------
__global__ __launch_bounds__(256) void k_attn_mfma(
    const ushort* __restrict__ qkv, const ushort* __restrict__ relb,
    ushort* __restrict__ ao) {
  __shared__ __align__(16) ushort Ks[64 * 72];
  __shared__ __align__(16) ushort Vt[64 * 72];
  __shared__ float qrl[64][66];
  __shared__ __align__(16) ushort Pl[4][16 * 72];
  int t = threadIdx.x, lane = t & 63, w = t >> 6;
  int h = blockIdx.y, b = blockIdx.z;
  int q0 = blockIdx.x * 64;
  size_t baseq = ((size_t)b * 1024) * 1536 + h * 64;
  size_t basek = baseq + 512;
  size_t basev = baseq + 1024;
  int qw = q0 + w * 16;
  int rl15 = lane & 15, l16 = lane >> 4;

  bf16x8 aq[2];
#pragma unroll
  for (int ks = 0; ks < 2; ks++)
    aq[ks] = *(const bf16x8*)(qkv + baseq + (size_t)(qw + rl15) * 1536 + ks * 32 + l16 * 8);

  // qrel[qrow][r] = Q . rel[r]
#pragma unroll
  for (int nb = 0; nb < 5; nb++) {
    f32x4 rc = {};
#pragma unroll
    for (int ks = 0; ks < 2; ks++) {
      bf16x8 rb = *(const bf16x8*)(relb + (size_t)(nb * 16 + rl15) * 64 + ks * 32 + l16 * 8);
      rc = __builtin_amdgcn_mfma_f32_16x16x32_bf16(aq[ks], rb, rc, 0, 0, 0);
    }
    int col = nb * 16 + rl15;
    if (col < 65) {
#pragma unroll
      for (int r = 0; r < 4; r++) qrl[w * 16 + l16 * 4 + r][col] = rc[r];
    }
  }

  float mrow[4], lrow[4];
  f32x4 oacc[4] = {};
#pragma unroll
  for (int r = 0; r < 4; r++) {
    mrow[r] = -1e30f;
    lrow[r] = 0.f;
  }

  for (int kb = 0; kb < 1024; kb += 64) {
    __syncthreads();
#pragma unroll
    for (int i = 0; i < 2; i++) {
      int c = t + i * 256;
      int key = c >> 3, dc = c & 7;
      bf16x8 kv = *(const bf16x8*)(qkv + basek + (size_t)(kb + key) * 1536 + dc * 8);
      *(bf16x8*)&Ks[key * 72 + dc * 8] = kv;
    }
#pragma unroll
    for (int i = 0; i < 2; i++) {
      int c = t + i * 256;
      int key = c & 63, dh = c >> 6;
      bf16x8 vv8 = *(const bf16x8*)(qkv + basev + (size_t)(kb + key) * 1536 + dh * 8);
#pragma unroll
      for (int e = 0; e < 8; e++) Vt[(dh * 8 + e) * 72 + key] = (ushort)vv8[e];
    }
    __syncthreads();

    f32x4 sacc[4] = {};
#pragma unroll
    for (int ks = 0; ks < 2; ks++) {
#pragma unroll
      for (int nb = 0; nb < 4; nb++) {
        bf16x8 bk8 = *(const bf16x8*)&Ks[(nb * 16 + rl15) * 72 + ks * 32 + l16 * 8];
        sacc[nb] = __builtin_amdgcn_mfma_f32_16x16x32_bf16(aq[ks], bk8, sacc[nb], 0, 0, 0);
      }
    }

    float p[4][4];
#pragma unroll
    for (int r = 0; r < 4; r++) {
      int rloc = l16 * 4 + r;
      int qg = q0 + w * 16 + rloc;
      float sv[4];
      float rowm = -1e30f;
#pragma unroll
      for (int nb = 0; nb < 4; nb++) {
        int kcol = kb + nb * 16 + rl15;
        int delta = kcol - qg;
        delta = delta < -32 ? -32 : (delta > 32 ? 32 : delta);
        float s_ = sacc[nb][r] * 0.125f + qrl[w * 16 + rloc][delta + 32];
        sv[nb] = s_;
        rowm = fmaxf(rowm, s_);
      }
#pragma unroll
      for (int msk = 1; msk <= 8; msk <<= 1)
        rowm = fmaxf(rowm, __shfl_xor(rowm, msk, 64));
      float mn = fmaxf(mrow[r], rowm);
      float scale = __expf(mrow[r] - mn);
      float ls = 0.f;
#pragma unroll
      for (int nb = 0; nb < 4; nb++) {
        float pv = __expf(sv[nb] - mn);
        p[nb][r] = pv;
        ls += pv;
      }
#pragma unroll
      for (int msk = 1; msk <= 8; msk <<= 1) ls += __shfl_xor(ls, msk, 64);
      lrow[r] = lrow[r] * scale + ls;
      mrow[r] = mn;
#pragma unroll
      for (int nb = 0; nb < 4; nb++) oacc[nb][r] *= scale;
    }

#pragma unroll
    for (int nb = 0; nb < 4; nb++)
#pragma unroll
      for (int r = 0; r < 4; r++)
        Pl[w][(l16 * 4 + r) * 72 + nb * 16 + rl15] = f2b(p[nb][r]);
#pragma unroll
    for (int ks = 0; ks < 2; ks++) {
      bf16x8 pa = *(const bf16x8*)&Pl[w][rl15 * 72 + ks * 32 + l16 * 8];
#pragma unroll
      for (int nb = 0; nb < 4; nb++) {
        bf16x8 bv8 = *(const bf16x8*)&Vt[(nb * 16 + rl15) * 72 + ks * 32 + l16 * 8];
        oacc[nb] = __builtin_amdgcn_mfma_f32_16x16x32_bf16(pa, bv8, oacc[nb], 0, 0, 0);
      }
    }
  }

  size_t baseo = ((size_t)b * 1024) * 512 + h * 64;
#pragma unroll
  for (int nb = 0; nb < 4; nb++) {
    int d = nb * 16 + rl15;
#pragma unroll
    for (int r = 0; r < 4; r++) {
      int row = q0 + w * 16 + l16 * 4 + r;
      ao[baseo + (size_t)row * 512 + d] = f2b(oacc[nb][r] / lrow[r]);
    }
  }
}

// ---------------------------------------------------------------------------
// Final global attention (fused qkv layout), last query row only.
// ---------------------------------------------------------------------------
__global__ __launch_bounds__(256) void k_gattn(
    const ushort* __restrict__ qkv, float* __restrict__ ctxa) {
  int t = threadIdx.x;
  int h = blockIdx.x & 7, b = blockIdx.x >> 3;
  __shared__ float Qs[64];
  __shared__ float sc[1024];
  __shared__ float red[4];
  __shared__ float op[4][64];
  if (t < 64) Qs[t] = b2f(qkv[(size_t)(b * 1024 + 1023) * 1536 + h * 64 + t]);
  __syncthreads();
  float lm = -1e30f;
  float sv[4];
#pragma unroll
  for (int jj = 0; jj < 4; jj++) {
    int j = t + (jj << 8);
    float s = 0.f;
#pragma unroll
    for (int d = 0; d < 64; d++)
      s += Qs[d] * b2f(qkv[(size_t)(b * 1024 + j) * 1536 + 512 + h * 64 + d]);
    s *= 0.125f;
    sv[jj] = s;
    lm = fmaxf(lm, s);
  }
  float bm = block_max(lm, red);
  float ls = 0.f;
#pragma unroll
  for (int jj = 0; jj < 4; jj++) {
    float e = __expf(sv[jj] - bm);
    sc[t + (jj << 8)] = e;
    ls += e;
  }
  float bs = block_sum(ls, red);
  int d = t & 63, qd = t >> 6;
  float acc = 0.f;
  for (int j = qd << 8; j < (qd << 8) + 256; j++)
    acc += sc[j] * b2f(qkv[(size_t)(b * 1024 + j) * 1536 + 1024 + h * 64 + d]);
  op[qd][d] = acc;
  __syncthreads();
  if (t < 64) {
    float r = (op[0][t] + op[1][t] + op[2][t] + op[3][t]) / bs;
    ctxa[b * 512 + h * 64 + t] = r;
  }
}

// ---------------------------------------------------------------------------
// 4-row GEMM (fp32): ctx = attnlast @ gWo + gbo
// ---------------------------------------------------------------------------
__global__ __launch_bounds__(256) void k_rowgemm(
    const float* __restrict__ xrow, const float* __restrict__ W,
    const float* __restrict__ bias, float* __restrict__ y) {
  int b = blockIdx.x;
  int t = threadIdx.x;
  __shared__ float xs[512];
  xs[t] = xrow[b * 512 + t];
  xs[t + 256] = xrow[b * 512 + t + 256];
  __syncthreads();
  float a0 = bias[t], a1 = bias[t + 256];
  for (int kk = 0; kk < 512; kk++) {
    float xv = xs[kk];
    a0 += xv * W[(size_t)kk * 512 + t];
    a1 += xv * W[(size_t)kk * 512 + t + 256];
  }
  y[b * 512 + t] = a0;
  y[b * 512 + t + 256] = a1;
}

// ---------------------------------------------------------------------------
// Head MLP (fp32)
// ---------------------------------------------------------------------------
__global__ __launch_bounds__(256) void k_head(
    const float* __restrict__ ctx, const float* __restrict__ hW1,
    const float* __restrict__ hb1, const float* __restrict__ hg,
    const float* __restrict__ hbt, const float* __restrict__ hW2,
    const float* __restrict__ hb2, float* __restrict__ out) {
  int b = blockIdx.x / 3, nh = blockIdx.x % 3;
  int t = threadIdx.x;
  __shared__ float cs[512];
  __shared__ float red[4];
  cs[t] = ctx[b * 512 + t];
  cs[t + 256] = ctx[b * 512 + t + 256];
  __syncthreads();
  float y = hb1[nh * 256 + t];
  for (int d = 0; d < 512; d++) y += cs[d] * hW1[((size_t)nh * 512 + d) * 256 + t];
  float mean = block_sum(y, red) * (1.f / 256.f);
  float dv = y - mean;
  float var = block_sum(dv * dv, red) * (1.f / 256.f);
  float rs = rsqrtf(var + 1e-5f);
  float yn = dv * rs * hg[nh * 256 + t] + hbt[nh * 256 + t];
  yn = fmaxf(yn, 0.f);
  float s = block_sum(yn * hW2[nh * 256 + t], red);
  if (t == 0) out[b * 3 + nh] = s + hb2[nh];
}

// ---------------------------------------------------------------------------
extern "C" void kernel_launch(void* const* d_in, const int* in_sizes, int n_in,
                              void* d_out, int out_size, void* d_ws, size_t ws_size,
                              hipStream_t stream) {
  const float* x = (const float*)d_in[0];
  const float* in_W = (const float*)d_in[1];
  const float* in_b = (const float*)d_in[2];
  const float* in_lng = (const float*)d_in[3];
  const float* in_lnb = (const float*)d_in[4];
  const float* ln1_g = (const float*)d_in[5];
  const float* ln1_b = (const float*)d_in[6];
  const float* Wq = (const float*)d_in[7];
  const float* bq = (const float*)d_in[8];
  const float* Wk = (const float*)d_in[9];
  const float* bk = (const float*)d_in[10];
  const float* Wv = (const float*)d_in[11];
  const float* bv = (const float*)d_in[12];
  const float* Wo = (const float*)d_in[13];
  const float* bo = (const float*)d_in[14];
  const float* rel = (const float*)d_in[15];
  const float* ln2_g = (const float*)d_in[16];
  const float* ln2_b = (const float*)d_in[17];
  const float* W1 = (const float*)d_in[18];
  const float* b1 = (const float*)d_in[19];
  const float* W2 = (const float*)d_in[20];
  const float* b2 = (const float*)d_in[21];
  const float* gWq = (const float*)d_in[22];
  const float* gbq = (const float*)d_in[23];
  const float* gWk = (const float*)d_in[24];
  const float* gbk = (const float*)d_in[25];
  const float* gWv = (const float*)d_in[26];
  const float* gbv = (const float*)d_in[27];
  const float* gWo = (const float*)d_in[28];
  const float* gbo = (const float*)d_in[29];
  const float* hW1 = (const float*)d_in[30];
  const float* hb1 = (const float*)d_in[31];
  const float* hlng = (const float*)d_in[32];
  const float* hlnb = (const float*)d_in[33];
  const float* hW2 = (const float*)d_in[34];
  const float* hb2 = (const float*)d_in[35];
  float* out = (float*)d_out;

  uint8_t* wsb = (uint8_t*)d_ws;
  const size_t MB = 1024 * 1024;
  float* h = (float*)(wsb + 0);              // 8 MB
  ushort* xn = (ushort*)(wsb + 8 * MB);      // 4 MB
  ushort* qkvb = (ushort*)(wsb + 12 * MB);   // 12 MB  [4096][1536]
  ushort* aob = (ushort*)(wsb + 24 * MB);    // 4 MB
  ushort* ffb = (ushort*)(wsb + 28 * MB);    // 16 MB  [4096][2048]
  ushort* wqkv = (ushort*)(wsb + 44 * MB);   // 4 x 1.5 MB
  ushort* wto = (ushort*)(wsb + 50 * MB);    // 4 x 0.5 MB
  ushort* wt1 = (ushort*)(wsb + 52 * MB);    // 4 x 2 MB
  ushort* wt2 = (ushort*)(wsb + 60 * MB);    // 4 x 2 MB
  ushort* gwqkv = (ushort*)(wsb + 68 * MB);  // 1.5 MB
  ushort* relb = (ushort*)(wsb + 70 * MB);   // 40 KB
  float* attnlast = (float*)(wsb + 71 * MB);
  float* ctx = attnlast + 4096;

  const size_t W55 = 512 * 512;  // elems per 512x512 matrix

  // ---- upfront weight prep (3 launches) ----
  {
    PJobs j{};
    for (int l = 0; l < 4; l++) {
      j.s[l * 4 + 0] = Wq + (size_t)l * W55;
      j.d[l * 4 + 0] = wqkv + (size_t)l * 1536 * 512;
      j.s[l * 4 + 1] = Wk + (size_t)l * W55;
      j.d[l * 4 + 1] = wqkv + (size_t)l * 1536 * 512 + 512 * 512;
      j.s[l * 4 + 2] = Wv + (size_t)l * W55;
      j.d[l * 4 + 2] = wqkv + (size_t)l * 1536 * 512 + 1024 * 512;
      j.s[l * 4 + 3] = Wo + (size_t)l * W55;
      j.d[l * 4 + 3] = wto + (size_t)l * W55;
    }
    j.s[16] = gWq; j.d[16] = gwqkv;
    j.s[17] = gWk; j.d[17] = gwqkv + 512 * 512;
    j.s[18] = gWv; j.d[18] = gwqkv + 1024 * 512;
    k_wprep<<<dim3(16, 16, 19), 256, 0, stream>>>(j, 512, 512);
  }
  {
    PJobs j{};
    for (int l = 0; l < 4; l++) {
      j.s[l] = W1 + (size_t)l * 512 * 2048;
      j.d[l] = wt1 + (size_t)l * 2048 * 512;
    }
    k_wprep<<<dim3(64, 16, 4), 256, 0, stream>>>(j, 512, 2048);
  }
  {
    PJobs j{};
    for (int l = 0; l < 4; l++) {
      j.s[l] = W2 + (size_t)l * 2048 * 512;
      j.d[l] = wt2 + (size_t)l * 512 * 2048;
    }
    k_wprep<<<dim3(16, 64, 4), 256, 0, stream>>>(j, 2048, 512);
  }
  k_relprep<<<dim3(20, 4), 256, 0, stream>>>(rel, relb);
  k_inproj<<<4096, 256, 0, stream>>>(x, in_W, in_b, in_lng, in_lnb, h);

  for (int l = 0; l < 4; l++) {
    size_t vo = (size_t)l * 512;
    k_lnb<<<4096, 256, 0, stream>>>(h, ln1_g + vo, ln1_b + vo, xn);
    // fused QKV: [4096][512] @ [1536][512]^T -> qkvb [4096][1536]
    k_mg<128, 0, 1><<<768, 256, 0, stream>>>(xn, wqkv + (size_t)l * 1536 * 512,
                                             bq + vo, bk + vo, bv + vo, qkvb,
                                             512, 1536, 24);
    k_attn_mfma<<<dim3(16, 8, 4), 256, 0, stream>>>(qkvb, relb + (size_t)l * 80 * 64, aob);
    k_mg<64, 1, 0><<<512, 256, 0, stream>>>(aob, wto + (size_t)l * W55,
                                            bo + vo, bo + vo, bo + vo, h, 512, 512, 8);
    k_lnb<<<4096, 256, 0, stream>>>(h, ln2_g + vo, ln2_b + vo, xn);
    k_mg<128, 2, 0><<<1024, 256, 0, stream>>>(xn, wt1 + (size_t)l * 2048 * 512,
                                              b1 + (size_t)l * 2048, nullptr, nullptr,
                                              ffb, 512, 2048, 32);
    k_mg<64, 1, 0><<<512, 256, 0, stream>>>(ffb, wt2 + (size_t)l * 512 * 2048,
                                            b2 + vo, b2 + vo, b2 + vo, h, 2048, 512, 8);
  }

  // final global attention
  k_cvt<<<8192, 256, 0, stream>>>(h, xn);
  k_mg<128, 0, 1><<<768, 256, 0, stream>>>(xn, gwqkv, gbq, gbk, gbv, qkvb, 512, 1536, 24);
  k_gattn<<<32, 256, 0, stream>>>(qkvb, attnlast);
  k_rowgemm<<<4, 256, 0, stream>>>(attnlast, gWo, gbo, ctx);
  k_head<<<12, 256, 0, stream>>>(ctx, hW1, hb1, hlng, hlnb, hW2, hb2, out);
}

// Round 4
// 621.885 us; speedup vs baseline: 8.6860x; 1.0150x over previous
//
#include <hip/hip_runtime.h>
#include <math.h>

#define DEV __device__ __forceinline__

// B=4, S=1024, F=20, D=512, H=8, L=4, FF=2048, M=32, NH=3, D2=256, O=1, HD=64
constexpr int BSD = 4 * 1024 * 512;  // B*S*D

typedef __attribute__((ext_vector_type(8))) short bf16x8;
typedef __attribute__((ext_vector_type(4))) float f32x4;

typedef __attribute__((address_space(1))) const void global_cvoid;
typedef __attribute__((address_space(3))) void lds_void;

DEV ushort f2b(float f) {
  union { float f; uint u; } x{f};
  uint r = x.u + 0x7fff + ((x.u >> 16) & 1);
  return (ushort)(r >> 16);
}
DEV float b2f(ushort u) {
  union { uint u; float f; } x{(uint)u << 16};
  return x.f;
}
DEV int swz128(int b) { return b ^ (((b >> 7) & 7) << 4); }

DEV float wave_sum(float v) {
#pragma unroll
  for (int m = 32; m >= 1; m >>= 1) v += __shfl_xor(v, m, 64);
  return v;
}
DEV float wave_max(float v) {
#pragma unroll
  for (int m = 32; m >= 1; m >>= 1) v = fmaxf(v, __shfl_xor(v, m, 64));
  return v;
}
DEV float block_sum(float v, float* sm) {
  v = wave_sum(v);
  __syncthreads();
  if ((threadIdx.x & 63) == 0) sm[threadIdx.x >> 6] = v;
  __syncthreads();
  return sm[0] + sm[1] + sm[2] + sm[3];
}
DEV float block_max(float v, float* sm) {
  v = wave_max(v);
  __syncthreads();
  if ((threadIdx.x & 63) == 0) sm[threadIdx.x >> 6] = v;
  __syncthreads();
  return fmaxf(fmaxf(sm[0], sm[1]), fmaxf(sm[2], sm[3]));
}

// ---------------------------------------------------------------------------
// Input projection (fp32 h): h = LN(x @ in_W + in_b)*g + b + posenc
// ---------------------------------------------------------------------------
__global__ __launch_bounds__(256) void k_inproj(
    const float* __restrict__ x, const float* __restrict__ W,
    const float* __restrict__ bias, const float* __restrict__ g,
    const float* __restrict__ bt, float* __restrict__ h) {
  int r = blockIdx.x;
  int s = r & 1023;
  int t = threadIdx.x;
  __shared__ float xr[20];
  __shared__ float red[4];
  if (t < 20) xr[t] = x[r * 20 + t];
  __syncthreads();
  float o0 = bias[t], o1 = bias[t + 256];
#pragma unroll
  for (int f = 0; f < 20; f++) {
    float xv = xr[f];
    o0 += xv * W[f * 512 + t];
    o1 += xv * W[f * 512 + t + 256];
  }
  float mean = block_sum(o0 + o1, red) * (1.f / 512.f);
  float d0 = o0 - mean, d1 = o1 - mean;
  float var = block_sum(d0 * d0 + d1 * d1, red) * (1.f / 512.f);
  float rs = rsqrtf(var + 1e-5f);
  float n0 = d0 * rs * g[t] + bt[t];
  float n1 = d1 * rs * g[t + 256] + bt[t + 256];
  const float c1 = -9.210340371976184f / 512.f;
  {
    int c = t;
    float div = expf((float)(c & ~1) * c1);
    float arg = (float)s * div;
    n0 += (c & 1) ? cosf(arg) : sinf(arg);
  }
  {
    int c = t + 256;
    float div = expf((float)(c & ~1) * c1);
    float arg = (float)s * div;
    n1 += (c & 1) ? cosf(arg) : sinf(arg);
  }
  float* hr = h + (size_t)r * 512;
  hr[t] = n0;
  hr[t + 256] = n1;
}

// ---------------------------------------------------------------------------
// LayerNorm fp32 -> bf16 out
// ---------------------------------------------------------------------------
__global__ __launch_bounds__(256) void k_lnb(
    const float* __restrict__ x, const float* __restrict__ g,
    const float* __restrict__ bt, ushort* __restrict__ y) {
  __shared__ float red[4];
  int r = blockIdx.x;
  int t = threadIdx.x;
  const float* xr = x + (size_t)r * 512;
  float v0 = xr[t], v1 = xr[t + 256];
  float mean = block_sum(v0 + v1, red) * (1.f / 512.f);
  float d0 = v0 - mean, d1 = v1 - mean;
  float var = block_sum(d0 * d0 + d1 * d1, red) * (1.f / 512.f);
  float rs = rsqrtf(var + 1e-5f);
  ushort* yr = y + (size_t)r * 512;
  yr[t] = f2b(d0 * rs * g[t] + bt[t]);
  yr[t + 256] = f2b(d1 * rs * g[t + 256] + bt[t + 256]);
}

// ---------------------------------------------------------------------------
// Weight prep: transpose+convert src[K][N] f32 -> dst[N][K] bf16, job table.
// ---------------------------------------------------------------------------
struct PJobs {
  const float* s[19];
  ushort* d[19];
};
__global__ __launch_bounds__(256) void k_wprep(PJobs j, int K, int N) {
  const float* src = j.s[blockIdx.z];
  ushort* dst = j.d[blockIdx.z];
  __shared__ float ld[32][33];
  int n0 = blockIdx.x * 32, k0 = blockIdx.y * 32;
  int c = threadIdx.x & 31, r0 = threadIdx.x >> 5;
#pragma unroll
  for (int i = 0; i < 4; i++)
    ld[r0 + i * 8][c] = src[(size_t)(k0 + r0 + i * 8) * N + n0 + c];
  __syncthreads();
#pragma unroll
  for (int i = 0; i < 4; i++)
    dst[(size_t)(n0 + r0 + i * 8) * K + k0 + c] = f2b(ld[c][r0 + i * 8]);
}

// rel [L][65][64] f32 -> [L][80][64] bf16 *8 (compensates Q prescale), pad 0
__global__ __launch_bounds__(256) void k_relprep(const float* __restrict__ rel,
                                                 ushort* __restrict__ relb) {
  int i = blockIdx.x * 256 + threadIdx.x;  // 0..5119
  int l = blockIdx.y;
  int r = i >> 6, d = i & 63;
  float v = (r < 65) ? rel[((size_t)l * 65 + r) * 64 + d] * 8.f : 0.f;
  relb[(size_t)l * 80 * 64 + i] = f2b(v);
}

// ---------------------------------------------------------------------------
// V transpose per (b,h): vT[bh][d][s] = qkv[b*1024+s][1024 + h*64 + d]
// grid (32 s-tiles, 2 d-tiles, 32 bh)
// ---------------------------------------------------------------------------
__global__ __launch_bounds__(256) void k_vprep(const ushort* __restrict__ qkv,
                                               ushort* __restrict__ vT) {
  int bh = blockIdx.z, b = bh >> 3, h = bh & 7;
  int s0 = blockIdx.x * 32, d0 = blockIdx.y * 32;
  __shared__ ushort td[32][33];
  int c = threadIdx.x & 31, r = threadIdx.x >> 5;
#pragma unroll
  for (int i = 0; i < 4; i++)
    td[r + i * 8][c] =
        qkv[(size_t)(b * 1024 + s0 + r + i * 8) * 1536 + 1024 + h * 64 + d0 + c];
  __syncthreads();
#pragma unroll
  for (int i = 0; i < 4; i++)
    vT[((size_t)bh * 64 + d0 + r + i * 8) * 1024 + s0 + c] = td[c][r + i * 8];
}

// ---------------------------------------------------------------------------
// bf16 MFMA GEMM: global_load_lds(16B) + source XOR swizzle, XCD-chunked grid.
// MODE 0: bf16 out; 1: fp32 residual in-place; 2: gelu bf16;
// 3: residual + bf16 copy to C2. FUSEB: QKV bias select + Q *= 0.125.
// ---------------------------------------------------------------------------
template <int BM, int BN, int MODE, int FUSEB>
__global__ __launch_bounds__(256) void k_mg(
    const ushort* __restrict__ A, const ushort* __restrict__ Bt,
    const float* __restrict__ bias0, const float* __restrict__ bias1,
    const float* __restrict__ bias2, void* __restrict__ Cv,
    ushort* __restrict__ C2, int K, int ldc, int gx) {
  constexpr int BK = 64;
  __shared__ __align__(16) ushort As[BM * BK];
  __shared__ __align__(16) ushort Bs[BN * BK];
  int nwg = gridDim.x;
  int id = blockIdx.x;
  int logical = (id & 7) * (nwg >> 3) + (id >> 3);
  int bx = logical % gx, by = logical / gx;
  int row0 = by * BM, col0 = bx * BN;
  int t = threadIdx.x, lane = t & 63, w = t >> 6;
  int rl15 = lane & 15, l16 = lane >> 4;
  constexpr int WR = (BM == 128 && BN == 128) ? 2 : BM / 32;
  constexpr int WC = 4 / WR;
  constexpr int MI = BM / (WR * 16);
  constexpr int NI = BN / (WC * 16);
  int wr = w % WR, wc = w / WR;
  int wrow = wr * MI * 16;
  int wcol = wc * NI * 16;
  f32x4 acc[MI][NI] = {};
  for (int kb = 0; kb < K; kb += BK) {
    __syncthreads();
#pragma unroll
    for (int i = 0; i < BM / 32; i++) {
      int blk = w * (BM / 32) + i;
      int lb = blk * 1024 + lane * 16;
      int lg = swz128(lb);
      int r = lg >> 7, cb = (lg & 127) >> 1;
      __builtin_amdgcn_global_load_lds(
          (global_cvoid*)(A + (size_t)(row0 + r) * K + kb + cb),
          (lds_void*)((char*)As + blk * 1024), 16, 0, 0);
    }
#pragma unroll
    for (int i = 0; i < BN / 32; i++) {
      int blk = w * (BN / 32) + i;
      int lb = blk * 1024 + lane * 16;
      int lg = swz128(lb);
      int r = lg >> 7, cb = (lg & 127) >> 1;
      __builtin_amdgcn_global_load_lds(
          (global_cvoid*)(Bt + (size_t)(col0 + r) * K + kb + cb),
          (lds_void*)((char*)Bs + blk * 1024), 16, 0, 0);
    }
    __syncthreads();
#pragma unroll
    for (int ks = 0; ks < 2; ks++) {
      bf16x8 af[MI], bfr[NI];
#pragma unroll
      for (int mi = 0; mi < MI; mi++) {
        int row = wrow + mi * 16 + rl15;
        af[mi] = *(const bf16x8*)((char*)As + swz128(row * 128 + ks * 64 + l16 * 16));
      }
#pragma unroll
      for (int ni = 0; ni < NI; ni++) {
        int row = wcol + ni * 16 + rl15;
        bfr[ni] = *(const bf16x8*)((char*)Bs + swz128(row * 128 + ks * 64 + l16 * 16));
      }
#pragma unroll
      for (int mi = 0; mi < MI; mi++)
#pragma unroll
        for (int ni = 0; ni < NI; ni++)
          acc[mi][ni] = __builtin_amdgcn_mfma_f32_16x16x32_bf16(af[mi], bfr[ni],
                                                                acc[mi][ni], 0, 0, 0);
    }
  }
#pragma unroll
  for (int mi = 0; mi < MI; mi++) {
#pragma unroll
    for (int ni = 0; ni < NI; ni++) {
      int col = col0 + wcol + ni * 16 + rl15;
      float bv;
      if (FUSEB) {
        const float* bp = bias0;
        int c = col;
        if (c >= 1024) { bp = bias2; c -= 1024; }
        else if (c >= 512) { bp = bias1; c -= 512; }
        bv = bp[c];
      } else {
        bv = bias0[col];
      }
#pragma unroll
      for (int r = 0; r < 4; r++) {
        int row = row0 + wrow + mi * 16 + l16 * 4 + r;
        float val = acc[mi][ni][r] + bv;
        if (FUSEB && col < 512) val *= 0.125f;  // fold 1/sqrt(HD) into Q
        if (MODE == 0) {
          ((ushort*)Cv)[(size_t)row * ldc + col] = f2b(val);
        } else if (MODE == 1) {
          float* Cp = (float*)Cv + (size_t)row * ldc + col;
          *Cp = *Cp + val;
        } else if (MODE == 2) {
          val = 0.5f * val * (1.f + erff(val * 0.70710678118654752f));
          ((ushort*)Cv)[(size_t)row * ldc + col] = f2b(val);
        } else {
          float* Cp = (float*)Cv + (size_t)row * ldc + col;
          float nv = *Cp + val;
          *Cp = nv;
          C2[(size_t)row * ldc + col] = f2b(nv);
        }
      }
    }
  }
}

// ---------------------------------------------------------------------------
// MFMA flash attention. Q prescaled by 1/8, rel prescaled by 8.
// K staged via global_load_lds (swizzled); V^T staged from vT (swizzled).
// grid (S/64, H, B), 4 waves, wave owns 16 q-rows.
// ---------------------------------------------------------------------------
__global__ __launch_bounds__(256) void k_attn_mfma(
    const ushort* __restrict__ qkv, const ushort* __restrict__ vT,
    const ushort* __restrict__ relb, ushort* __restrict__ ao) {
  __shared__ __align__(16) ushort Ks[64 * 64];
  __shared__ __align__(16) ushort Vts[64 * 64];
  __shared__ ushort qrlb[64][66];
  __shared__ __align__(16) ushort Pl[4][16 * 72];
  int t = threadIdx.x, lane = t & 63, w = t >> 6;
  int h = blockIdx.y, b = blockIdx.z;
  int q0 = blockIdx.x * 64;
  size_t baseq = ((size_t)b * 1024) * 1536 + h * 64;
  size_t basek = baseq + 512;
  const ushort* vTb = vT + ((size_t)(b * 8 + h)) * 64 * 1024;
  int qw = q0 + w * 16;
  int rl15 = lane & 15, l16 = lane >> 4;

  bf16x8 aq[2];
#pragma unroll
  for (int ks = 0; ks < 2; ks++)
    aq[ks] = *(const bf16x8*)(qkv + baseq + (size_t)(qw + rl15) * 1536 + ks * 32 + l16 * 8);

  // qrl[qrow][r] = Q' . rel'[r]  (= q.rel unscaled)
#pragma unroll
  for (int nb = 0; nb < 5; nb++) {
    f32x4 rc = {};
#pragma unroll
    for (int ks = 0; ks < 2; ks++) {
      bf16x8 rb = *(const bf16x8*)(relb + (size_t)(nb * 16 + rl15) * 64 + ks * 32 + l16 * 8);
      rc = __builtin_amdgcn_mfma_f32_16x16x32_bf16(aq[ks], rb, rc, 0, 0, 0);
    }
    int col = nb * 16 + rl15;
    if (col < 65) {
#pragma unroll
      for (int r = 0; r < 4; r++) qrlb[w * 16 + l16 * 4 + r][col] = f2b(rc[r]);
    }
  }

  float mrow[4], lrow[4];
  f32x4 oacc[4] = {};
#pragma unroll
  for (int r = 0; r < 4; r++) {
    mrow[r] = -1e30f;
    lrow[r] = 0.f;
  }

  for (int kb = 0; kb < 1024; kb += 64) {
    __syncthreads();
    // stage K tile and V^T tile, 8 x 1KB blocks each, 2 per wave
#pragma unroll
    for (int i = 0; i < 2; i++) {
      int blk = w * 2 + i;
      int lb = blk * 1024 + lane * 16;
      int lg = swz128(lb);
      int r = lg >> 7, cb = (lg & 127) >> 1;
      __builtin_amdgcn_global_load_lds(
          (global_cvoid*)(qkv + basek + (size_t)(kb + r) * 1536 + cb),
          (lds_void*)((char*)Ks + blk * 1024), 16, 0, 0);
      __builtin_amdgcn_global_load_lds(
          (global_cvoid*)(vTb + (size_t)r * 1024 + kb + cb),
          (lds_void*)((char*)Vts + blk * 1024), 16, 0, 0);
    }
    __syncthreads();

    f32x4 sacc[4] = {};
#pragma unroll
    for (int ks = 0; ks < 2; ks++) {
#pragma unroll
      for (int nb = 0; nb < 4; nb++) {
        bf16x8 bk8 = *(const bf16x8*)((char*)Ks +
                                      swz128((nb * 16 + rl15) * 128 + ks * 64 + l16 * 16));
        sacc[nb] = __builtin_amdgcn_mfma_f32_16x16x32_bf16(aq[ks], bk8, sacc[nb], 0, 0, 0);
      }
    }

    // rel add: uniform fast path (wave-uniform branch) vs banded path
    float sv[4][4];
    bool hiU = (kb >= qw + 47);
    bool loU = (kb + 95 <= qw);
    if (hiU || loU) {
      int idx = hiU ? 64 : 0;
#pragma unroll
      for (int r = 0; r < 4; r++) {
        float crow = b2f(qrlb[w * 16 + l16 * 4 + r][idx]);
#pragma unroll
        for (int nb = 0; nb < 4; nb++) sv[r][nb] = sacc[nb][r] + crow;
      }
    } else {
#pragma unroll
      for (int r = 0; r < 4; r++) {
        int rloc = l16 * 4 + r;
        int qg = q0 + w * 16 + rloc;
#pragma unroll
        for (int nb = 0; nb < 4; nb++) {
          int delta = kb + nb * 16 + rl15 - qg;
          delta = delta < -32 ? -32 : (delta > 32 ? 32 : delta);
          sv[r][nb] = sacc[nb][r] + b2f(qrlb[w * 16 + rloc][delta + 32]);
        }
      }
    }

    float p[4][4];
#pragma unroll
    for (int r = 0; r < 4; r++) {
      float rowm = fmaxf(fmaxf(sv[r][0], sv[r][1]), fmaxf(sv[r][2], sv[r][3]));
#pragma unroll
      for (int msk = 1; msk <= 8; msk <<= 1)
        rowm = fmaxf(rowm, __shfl_xor(rowm, msk, 64));
      if (rowm > mrow[r]) {  // rescale only when max grows
        float scale = __expf(mrow[r] - rowm);
        mrow[r] = rowm;
        lrow[r] *= scale;
#pragma unroll
        for (int nb = 0; nb < 4; nb++) oacc[nb][r] *= scale;
      }
      float ls = 0.f;
#pragma unroll
      for (int nb = 0; nb < 4; nb++) {
        float pv = __expf(sv[r][nb] - mrow[r]);
        p[nb][r] = pv;
        ls += pv;
      }
#pragma unroll
      for (int msk = 1; msk <= 8; msk <<= 1) ls += __shfl_xor(ls, msk, 64);
      lrow[r] += ls;
    }

    // P -> wave-private LDS (C-layout), re-read as A-frags
#pragma unroll
    for (int nb = 0; nb < 4; nb++)
#pragma unroll
      for (int r = 0; r < 4; r++)
        Pl[w][(l16 * 4 + r) * 72 + nb * 16 + rl15] = f2b(p[nb][r]);
#pragma unroll
    for (int ks = 0; ks < 2; ks++) {
      bf16x8 pa = *(const bf16x8*)&Pl[w][rl15 * 72 + ks * 32 + l16 * 8];
#pragma unroll
      for (int nb = 0; nb < 4; nb++) {
        bf16x8 bv8 = *(const bf16x8*)((char*)Vts +
                                      swz128((nb * 16 + rl15) * 128 + ks * 64 + l16 * 16));
        oacc[nb] = __builtin_amdgcn_mfma_f32_16x16x32_bf16(pa, bv8, oacc[nb], 0, 0, 0);
      }
    }
  }

  size_t baseo = ((size_t)b * 1024) * 512 + h * 64;
#pragma unroll
  for (int nb = 0; nb < 4; nb++) {
    int d = nb * 16 + rl15;
#pragma unroll
    for (int r = 0; r < 4; r++) {
      int row = q0 + w * 16 + l16 * 4 + r;
      ao[baseo + (size_t)row * 512 + d] = f2b(oacc[nb][r] / lrow[r]);
    }
  }
}

// ---------------------------------------------------------------------------
// Final global attention (fused qkv layout, Q prescaled), last query row.
// ---------------------------------------------------------------------------
__global__ __launch_bounds__(256) void k_gattn(
    const ushort* __restrict__ qkv, float* __restrict__ ctxa) {
  int t = threadIdx.x;
  int h = blockIdx.x & 7, b = blockIdx.x >> 3;
  __shared__ float Qs[64];
  __shared__ float sc[1024];
  __shared__ float red[4];
  __shared__ float op[4][64];
  if (t < 64) Qs[t] = b2f(qkv[(size_t)(b * 1024 + 1023) * 1536 + h * 64 + t]);
  __syncthreads();
  float lm = -1e30f;
  float sv[4];
#pragma unroll
  for (int jj = 0; jj < 4; jj++) {
    int j = t + (jj << 8);
    float s = 0.f;
#pragma unroll
    for (int d = 0; d < 64; d++)
      s += Qs[d] * b2f(qkv[(size_t)(b * 1024 + j) * 1536 + 512 + h * 64 + d]);
    sv[jj] = s;  // Q already scaled by 1/8
    lm = fmaxf(lm, s);
  }
  float bm = block_max(lm, red);
  float ls = 0.f;
#pragma unroll
  for (int jj = 0; jj < 4; jj++) {
    float e = __expf(sv[jj] - bm);
    sc[t + (jj << 8)] = e;
    ls += e;
  }
  float bs = block_sum(ls, red);
  int d = t & 63, qd = t >> 6;
  float acc = 0.f;
  for (int j = qd << 8; j < (qd << 8) + 256; j++)
    acc += sc[j] * b2f(qkv[(size_t)(b * 1024 + j) * 1536 + 1024 + h * 64 + d]);
  op[qd][d] = acc;
  __syncthreads();
  if (t < 64) {
    float r = (op[0][t] + op[1][t] + op[2][t] + op[3][t]) / bs;
    ctxa[b * 512 + h * 64 + t] = r;
  }
}

// ---------------------------------------------------------------------------
// 4-row GEMM (fp32): ctx = attnlast @ gWo + gbo
// ---------------------------------------------------------------------------
__global__ __launch_bounds__(256) void k_rowgemm(
    const float* __restrict__ xrow, const float* __restrict__ W,
    const float* __restrict__ bias, float* __restrict__ y) {
  int b = blockIdx.x;
  int t = threadIdx.x;
  __shared__ float xs[512];
  xs[t] = xrow[b * 512 + t];
  xs[t + 256] = xrow[b * 512 + t + 256];
  __syncthreads();
  float a0 = bias[t], a1 = bias[t + 256];
  for (int kk = 0; kk < 512; kk++) {
    float xv = xs[kk];
    a0 += xv * W[(size_t)kk * 512 + t];
    a1 += xv * W[(size_t)kk * 512 + t + 256];
  }
  y[b * 512 + t] = a0;
  y[b * 512 + t + 256] = a1;
}

// ---------------------------------------------------------------------------
// Head MLP (fp32)
// ---------------------------------------------------------------------------
__global__ __launch_bounds__(256) void k_head(
    const float* __restrict__ ctx, const float* __restrict__ hW1,
    const float* __restrict__ hb1, const float* __restrict__ hg,
    const float* __restrict__ hbt, const float* __restrict__ hW2,
    const float* __restrict__ hb2, float* __restrict__ out) {
  int b = blockIdx.x / 3, nh = blockIdx.x % 3;
  int t = threadIdx.x;
  __shared__ float cs[512];
  __shared__ float red[4];
  cs[t] = ctx[b * 512 + t];
  cs[t + 256] = ctx[b * 512 + t + 256];
  __syncthreads();
  float y = hb1[nh * 256 + t];
  for (int d = 0; d < 512; d++) y += cs[d] * hW1[((size_t)nh * 512 + d) * 256 + t];
  float mean = block_sum(y, red) * (1.f / 256.f);
  float dv = y - mean;
  float var = block_sum(dv * dv, red) * (1.f / 256.f);
  float rs = rsqrtf(var + 1e-5f);
  float yn = dv * rs * hg[nh * 256 + t] + hbt[nh * 256 + t];
  yn = fmaxf(yn, 0.f);
  float s = block_sum(yn * hW2[nh * 256 + t], red);
  if (t == 0) out[b * 3 + nh] = s + hb2[nh];
}

// ---------------------------------------------------------------------------
extern "C" void kernel_launch(void* const* d_in, const int* in_sizes, int n_in,
                              void* d_out, int out_size, void* d_ws, size_t ws_size,
                              hipStream_t stream) {
  const float* x = (const float*)d_in[0];
  const float* in_W = (const float*)d_in[1];
  const float* in_b = (const float*)d_in[2];
  const float* in_lng = (const float*)d_in[3];
  const float* in_lnb = (const float*)d_in[4];
  const float* ln1_g = (const float*)d_in[5];
  const float* ln1_b = (const float*)d_in[6];
  const float* Wq = (const float*)d_in[7];
  const float* bq = (const float*)d_in[8];
  const float* Wk = (const float*)d_in[9];
  const float* bk = (const float*)d_in[10];
  const float* Wv = (const float*)d_in[11];
  const float* bv = (const float*)d_in[12];
  const float* Wo = (const float*)d_in[13];
  const float* bo = (const float*)d_in[14];
  const float* rel = (const float*)d_in[15];
  const float* ln2_g = (const float*)d_in[16];
  const float* ln2_b = (const float*)d_in[17];
  const float* W1 = (const float*)d_in[18];
  const float* b1 = (const float*)d_in[19];
  const float* W2 = (const float*)d_in[20];
  const float* b2 = (const float*)d_in[21];
  const float* gWq = (const float*)d_in[22];
  const float* gbq = (const float*)d_in[23];
  const float* gWk = (const float*)d_in[24];
  const float* gbk = (const float*)d_in[25];
  const float* gWv = (const float*)d_in[26];
  const float* gbv = (const float*)d_in[27];
  const float* gWo = (const float*)d_in[28];
  const float* gbo = (const float*)d_in[29];
  const float* hW1 = (const float*)d_in[30];
  const float* hb1 = (const float*)d_in[31];
  const float* hlng = (const float*)d_in[32];
  const float* hlnb = (const float*)d_in[33];
  const float* hW2 = (const float*)d_in[34];
  const float* hb2 = (const float*)d_in[35];
  float* out = (float*)d_out;

  uint8_t* wsb = (uint8_t*)d_ws;
  const size_t MB = 1024 * 1024;
  float* h = (float*)(wsb + 0);              // 8 MB
  ushort* xn = (ushort*)(wsb + 8 * MB);      // 4 MB
  ushort* qkvb = (ushort*)(wsb + 12 * MB);   // 12 MB  [4096][1536]
  ushort* aob = (ushort*)(wsb + 24 * MB);    // 4 MB
  ushort* ffb = (ushort*)(wsb + 28 * MB);    // 16 MB  [4096][2048]
  ushort* vTb = ffb;                         // 4 MB, time-shared with ffb
  ushort* wqkv = (ushort*)(wsb + 44 * MB);   // 4 x 1.5 MB
  ushort* wto = (ushort*)(wsb + 50 * MB);    // 4 x 0.5 MB
  ushort* wt1 = (ushort*)(wsb + 52 * MB);    // 4 x 2 MB
  ushort* wt2 = (ushort*)(wsb + 60 * MB);    // 4 x 2 MB
  ushort* gwqkv = (ushort*)(wsb + 68 * MB);  // 1.5 MB
  ushort* relb = (ushort*)(wsb + 70 * MB);   // 40 KB
  float* attnlast = (float*)(wsb + 71 * MB);
  float* ctx = attnlast + 4096;

  const size_t W55 = 512 * 512;

  // ---- upfront weight prep ----
  {
    PJobs j{};
    for (int l = 0; l < 4; l++) {
      j.s[l * 4 + 0] = Wq + (size_t)l * W55;
      j.d[l * 4 + 0] = wqkv + (size_t)l * 1536 * 512;
      j.s[l * 4 + 1] = Wk + (size_t)l * W55;
      j.d[l * 4 + 1] = wqkv + (size_t)l * 1536 * 512 + 512 * 512;
      j.s[l * 4 + 2] = Wv + (size_t)l * W55;
      j.d[l * 4 + 2] = wqkv + (size_t)l * 1536 * 512 + 1024 * 512;
      j.s[l * 4 + 3] = Wo + (size_t)l * W55;
      j.d[l * 4 + 3] = wto + (size_t)l * W55;
    }
    j.s[16] = gWq; j.d[16] = gwqkv;
    j.s[17] = gWk; j.d[17] = gwqkv + 512 * 512;
    j.s[18] = gWv; j.d[18] = gwqkv + 1024 * 512;
    k_wprep<<<dim3(16, 16, 19), 256, 0, stream>>>(j, 512, 512);
  }
  {
    PJobs j{};
    for (int l = 0; l < 4; l++) {
      j.s[l] = W1 + (size_t)l * 512 * 2048;
      j.d[l] = wt1 + (size_t)l * 2048 * 512;
    }
    k_wprep<<<dim3(64, 16, 4), 256, 0, stream>>>(j, 512, 2048);
  }
  {
    PJobs j{};
    for (int l = 0; l < 4; l++) {
      j.s[l] = W2 + (size_t)l * 2048 * 512;
      j.d[l] = wt2 + (size_t)l * 512 * 2048;
    }
    k_wprep<<<dim3(16, 64, 4), 256, 0, stream>>>(j, 2048, 512);
  }
  k_relprep<<<dim3(20, 4), 256, 0, stream>>>(rel, relb);
  k_inproj<<<4096, 256, 0, stream>>>(x, in_W, in_b, in_lng, in_lnb, h);

  for (int l = 0; l < 4; l++) {
    size_t vo = (size_t)l * 512;
    k_lnb<<<4096, 256, 0, stream>>>(h, ln1_g + vo, ln1_b + vo, xn);
    k_mg<128, 64, 0, 1><<<768, 256, 0, stream>>>(xn, wqkv + (size_t)l * 1536 * 512,
                                                 bq + vo, bk + vo, bv + vo, qkvb,
                                                 nullptr, 512, 1536, 24);
    k_vprep<<<dim3(32, 2, 32), 256, 0, stream>>>(qkvb, vTb);
    k_attn_mfma<<<dim3(16, 8, 4), 256, 0, stream>>>(qkvb, vTb,
                                                    relb + (size_t)l * 80 * 64, aob);
    k_mg<64, 64, 1, 0><<<512, 256, 0, stream>>>(aob, wto + (size_t)l * W55, bo + vo,
                                                nullptr, nullptr, h, nullptr, 512, 512, 8);
    k_lnb<<<4096, 256, 0, stream>>>(h, ln2_g + vo, ln2_b + vo, xn);
    k_mg<128, 128, 2, 0><<<512, 256, 0, stream>>>(xn, wt1 + (size_t)l * 2048 * 512,
                                                  b1 + (size_t)l * 2048, nullptr, nullptr,
                                                  ffb, nullptr, 512, 2048, 16);
    if (l < 3)
      k_mg<64, 64, 1, 0><<<512, 256, 0, stream>>>(ffb, wt2 + (size_t)l * 512 * 2048,
                                                  b2 + vo, nullptr, nullptr, h, nullptr,
                                                  2048, 512, 8);
    else
      k_mg<64, 64, 3, 0><<<512, 256, 0, stream>>>(ffb, wt2 + (size_t)l * 512 * 2048,
                                                  b2 + vo, nullptr, nullptr, h, xn,
                                                  2048, 512, 8);
  }

  // final global attention (xn = bf16 copy of final h, from MODE 3)
  k_mg<128, 64, 0, 1><<<768, 256, 0, stream>>>(xn, gwqkv, gbq, gbk, gbv, qkvb,
                                               nullptr, 512, 1536, 24);
  k_gattn<<<32, 256, 0, stream>>>(qkvb, attnlast);
  k_rowgemm<<<4, 256, 0, stream>>>(attnlast, gWo, gbo, ctx);
  k_head<<<12, 256, 0, stream>>>(ctx, hW1, hb1, hlng, hlnb, hW2, hb2, out);
}